// Round 1
// baseline (1056.141 us; speedup 1.0000x reference)
//
#include <hip/hip_runtime.h>
#include <math.h>

#define Bx 8
#define Cx 512
#define Dx 256
#define Tx 2048
#define EPSx 1e-5f

// ---------------------------------------------------------------------------
// Generic 64x64-tile fp32 GEMM, A row-major (k contiguous):
//   O[b][m*Tx + n] = sum_k A[b*aBatch + m*K + k] * Bm[b*bBatch + k*Tx + n] (+ bias[m])
// 256 threads, 4x4 micro-tile per thread, K-chunk 16.
// ---------------------------------------------------------------------------
__global__ __launch_bounds__(256)
void gemm_rowA(const float* __restrict__ A, size_t aBatch,
               const float* __restrict__ Bm, size_t bBatch,
               const float* __restrict__ bias,
               float* __restrict__ O, size_t oBatch, int K) {
    __shared__ float As[16][65];   // +1 pad: store pattern hits banks (kk+mm)%32
    __shared__ float Bs[16][65];
    const int tid = threadIdx.x;
    const int tx = tid & 15, ty = tid >> 4;
    const int n0 = blockIdx.x * 64, m0 = blockIdx.y * 64;
    const int b  = blockIdx.z;
    const float* Ab = A + (size_t)b * aBatch;
    const float* Bb = Bm + (size_t)b * bBatch;
    float* Ob = O + (size_t)b * oBatch;

    const int ka = tid & 15, ma = tid >> 4;   // A-tile load mapping
    const int nb = tid & 63, kb = tid >> 6;   // B-tile load mapping

    float acc[4][4] = {};
    for (int k0 = 0; k0 < K; k0 += 16) {
#pragma unroll
        for (int i = 0; i < 4; i++) {
            int mm = ma + 16 * i;
            As[ka][mm] = Ab[(size_t)(m0 + mm) * K + (k0 + ka)];
        }
#pragma unroll
        for (int i = 0; i < 4; i++) {
            int kk = kb + 4 * i;
            Bs[kk][nb] = Bb[(size_t)(k0 + kk) * Tx + (n0 + nb)];
        }
        __syncthreads();
#pragma unroll
        for (int kk = 0; kk < 16; kk++) {
            float ar[4], br[4];
#pragma unroll
            for (int a = 0; a < 4; a++) ar[a] = As[kk][ty + 16 * a];
#pragma unroll
            for (int q = 0; q < 4; q++) br[q] = Bs[kk][tx + 16 * q];
#pragma unroll
            for (int a = 0; a < 4; a++)
#pragma unroll
                for (int q = 0; q < 4; q++)
                    acc[a][q] = fmaf(ar[a], br[q], acc[a][q]);
        }
        __syncthreads();
    }
#pragma unroll
    for (int a = 0; a < 4; a++) {
        int m = m0 + ty + 16 * a;
        float bv = bias ? bias[m] : 0.0f;
#pragma unroll
        for (int q = 0; q < 4; q++)
            Ob[(size_t)m * Tx + (n0 + tx + 16 * q)] = acc[a][q] + bv;
    }
}

// ---------------------------------------------------------------------------
// Same tile, but A stored k-major (A[b][k*Tx + m], M == Tx). Used for logits:
//   W[b][t*Tx + s] = sum_d th[b][d*Tx + t] * ph[b][d*Tx + s]
// ---------------------------------------------------------------------------
__global__ __launch_bounds__(256)
void gemm_kmajA(const float* __restrict__ A, size_t aBatch,
                const float* __restrict__ Bm, size_t bBatch,
                float* __restrict__ O, size_t oBatch, int K) {
    __shared__ float As[16][65];
    __shared__ float Bs[16][65];
    const int tid = threadIdx.x;
    const int tx = tid & 15, ty = tid >> 4;
    const int n0 = blockIdx.x * 64, m0 = blockIdx.y * 64;
    const int b  = blockIdx.z;
    const float* Ab = A + (size_t)b * aBatch;
    const float* Bb = Bm + (size_t)b * bBatch;
    float* Ob = O + (size_t)b * oBatch;

    const int mn = tid & 63, ka4 = tid >> 6;  // both tiles are k-major: same mapping

    float acc[4][4] = {};
    for (int k0 = 0; k0 < K; k0 += 16) {
#pragma unroll
        for (int i = 0; i < 4; i++) {
            int kk = ka4 + 4 * i;
            As[kk][mn] = Ab[(size_t)(k0 + kk) * Tx + (m0 + mn)];
        }
#pragma unroll
        for (int i = 0; i < 4; i++) {
            int kk = ka4 + 4 * i;
            Bs[kk][mn] = Bb[(size_t)(k0 + kk) * Tx + (n0 + mn)];
        }
        __syncthreads();
#pragma unroll
        for (int kk = 0; kk < 16; kk++) {
            float ar[4], br[4];
#pragma unroll
            for (int a = 0; a < 4; a++) ar[a] = As[kk][ty + 16 * a];
#pragma unroll
            for (int q = 0; q < 4; q++) br[q] = Bs[kk][tx + 16 * q];
#pragma unroll
            for (int a = 0; a < 4; a++)
#pragma unroll
                for (int q = 0; q < 4; q++)
                    acc[a][q] = fmaf(ar[a], br[q], acc[a][q]);
        }
        __syncthreads();
    }
#pragma unroll
    for (int a = 0; a < 4; a++) {
        int m = m0 + ty + 16 * a;
#pragma unroll
        for (int q = 0; q < 4; q++)
            Ob[(size_t)m * Tx + (n0 + tx + 16 * q)] = acc[a][q];
    }
}

// ---------------------------------------------------------------------------
// Row softmax over s for W[b*Tx + t][0..Tx). One block per row.
// ---------------------------------------------------------------------------
__global__ __launch_bounds__(256)
void softmax_rows(float* __restrict__ Wbuf) {
    float* row = Wbuf + (size_t)blockIdx.x * Tx;
    const int tid = threadIdx.x;
    float v[8];
    float mx = -3.4e38f;
#pragma unroll
    for (int i = 0; i < 8; i++) {
        v[i] = row[tid + 256 * i];
        mx = fmaxf(mx, v[i]);
    }
#pragma unroll
    for (int off = 32; off; off >>= 1) mx = fmaxf(mx, __shfl_xor(mx, off));
    __shared__ float redm[4], reds[4];
    if ((tid & 63) == 0) redm[tid >> 6] = mx;
    __syncthreads();
    mx = fmaxf(fmaxf(redm[0], redm[1]), fmaxf(redm[2], redm[3]));

    float s = 0.0f;
#pragma unroll
    for (int i = 0; i < 8; i++) {
        v[i] = __expf(v[i] - mx);
        s += v[i];
    }
#pragma unroll
    for (int off = 32; off; off >>= 1) s += __shfl_xor(s, off);
    if ((tid & 63) == 0) reds[tid >> 6] = s;
    __syncthreads();
    s = reds[0] + reds[1] + reds[2] + reds[3];
    float inv = 1.0f / s;
#pragma unroll
    for (int i = 0; i < 8; i++) row[tid + 256 * i] = v[i] * inv;
}

// ---------------------------------------------------------------------------
// Per-channel batch-norm stats over (B, T): one block per channel.
// ---------------------------------------------------------------------------
__global__ __launch_bounds__(256)
void bn_stats(const float* __restrict__ h, float* __restrict__ mean,
              float* __restrict__ rsig) {
    const int c = blockIdx.x;
    const int tid = threadIdx.x;
    float s = 0.0f, ss = 0.0f;
    for (int b = 0; b < Bx; b++) {
        const float* p = h + ((size_t)b * Cx + c) * Tx;
        for (int t = tid; t < Tx; t += 256) {
            float x = p[t];
            s += x;
            ss = fmaf(x, x, ss);
        }
    }
#pragma unroll
    for (int off = 32; off; off >>= 1) {
        s  += __shfl_xor(s, off);
        ss += __shfl_xor(ss, off);
    }
    __shared__ float rs[4], rss[4];
    if ((tid & 63) == 0) { rs[tid >> 6] = s; rss[tid >> 6] = ss; }
    __syncthreads();
    if (tid == 0) {
        s  = rs[0] + rs[1] + rs[2] + rs[3];
        ss = rss[0] + rss[1] + rss[2] + rss[3];
        const float invN = 1.0f / (float)(Bx * Tx);
        float mu  = s * invN;
        float var = ss * invN - mu * mu;
        mean[c] = mu;
        rsig[c] = rsqrtf(var + EPSx);
    }
}

// ---------------------------------------------------------------------------
// out = inpt + gamma*(h-mean)*rsig + beta   (float4 vectorized; T%4==0 so the
// channel index is constant within a float4)
// ---------------------------------------------------------------------------
__global__ __launch_bounds__(256)
void bn_apply(const float* __restrict__ inpt, const float* __restrict__ h,
              const float* __restrict__ mean, const float* __restrict__ rsig,
              const float* __restrict__ gamma, const float* __restrict__ beta,
              float* __restrict__ out) {
    size_t i = (size_t)blockIdx.x * 256 + threadIdx.x;  // float4 index
    int c = (int)((i / (Tx / 4)) % Cx);
    float4 x  = ((const float4*)inpt)[i];
    float4 hv = ((const float4*)h)[i];
    float mu = mean[c], rv = rsig[c], ga = gamma[c], be = beta[c];
    float4 o;
    o.x = x.x + ga * (hv.x - mu) * rv + be;
    o.y = x.y + ga * (hv.y - mu) * rv + be;
    o.z = x.z + ga * (hv.z - mu) * rv + be;
    o.w = x.w + ga * (hv.w - mu) * rv + be;
    ((float4*)out)[i] = o;
}

// ---------------------------------------------------------------------------
// Workspace layout (floats):
//   th   @ 0          4,194,304   (B*D*T)   -> later reused as attn
//   ph   @ 4194304    4,194,304             -> later reused as h (first half)
//   gg   @ 8388608    4,194,304             -> later reused as h (second half)
//   W    @ 12582912  33,554,432   (B*T*T)
//   mean @ 46137344   512
//   rsig @ 46137856   512
// total 46,138,368 floats = 184.6 MB
// ---------------------------------------------------------------------------
extern "C" void kernel_launch(void* const* d_in, const int* in_sizes, int n_in,
                              void* d_out, int out_size, void* d_ws, size_t ws_size,
                              hipStream_t stream) {
    const float* inpt    = (const float*)d_in[0];
    const float* theta_w = (const float*)d_in[1];
    const float* theta_b = (const float*)d_in[2];
    const float* phi_w   = (const float*)d_in[3];
    const float* phi_b   = (const float*)d_in[4];
    const float* g_w     = (const float*)d_in[5];
    const float* g_b     = (const float*)d_in[6];
    const float* ht_w    = (const float*)d_in[7];
    const float* ht_b    = (const float*)d_in[8];
    const float* gamma   = (const float*)d_in[9];
    const float* beta    = (const float*)d_in[10];

    float* ws   = (float*)d_ws;
    float* th   = ws;
    float* ph   = ws + 4194304;
    float* gg   = ws + 8388608;
    float* Wb   = ws + 12582912;
    float* attn = th;              // reuse after logits consumed th/ph
    float* h    = ph;              // spans ph+gg (exactly B*C*T floats)
    float* mean = Wb + (size_t)Bx * Tx * Tx;
    float* rsig = mean + Cx;

    const size_t sIn   = (size_t)Cx * Tx;   // inpt per-batch
    const size_t sProj = (size_t)Dx * Tx;   // theta/phi/g/attn per-batch
    const size_t sW    = (size_t)Tx * Tx;   // W per-batch
    const size_t sH    = (size_t)Cx * Tx;   // h per-batch

    dim3 blk(256);
    // Projections: (D x C) x (C x T) per batch
    gemm_rowA<<<dim3(Tx / 64, Dx / 64, Bx), blk, 0, stream>>>(
        theta_w, 0, inpt, sIn, theta_b, th, sProj, Cx);
    gemm_rowA<<<dim3(Tx / 64, Dx / 64, Bx), blk, 0, stream>>>(
        phi_w, 0, inpt, sIn, phi_b, ph, sProj, Cx);
    gemm_rowA<<<dim3(Tx / 64, Dx / 64, Bx), blk, 0, stream>>>(
        g_w, 0, inpt, sIn, g_b, gg, sProj, Cx);
    // Logits: W[b,t,s] = sum_d th[b,d,t]*ph[b,d,s]
    gemm_kmajA<<<dim3(Tx / 64, Tx / 64, Bx), blk, 0, stream>>>(
        th, sProj, ph, sProj, Wb, sW, Dx);
    // Row softmax over s
    softmax_rows<<<Bx * Tx, blk, 0, stream>>>(Wb);
    // attn[b,d,s] = sum_t gg[b,d,t]*W[b,t,s]
    gemm_rowA<<<dim3(Tx / 64, Dx / 64, Bx), blk, 0, stream>>>(
        gg, sProj, Wb, sW, nullptr, attn, sProj, Tx);
    // h[b,c,t] = sum_d ht_w[c,d]*attn[b,d,t] + ht_b[c]
    gemm_rowA<<<dim3(Tx / 64, Cx / 64, Bx), blk, 0, stream>>>(
        ht_w, 0, attn, sProj, ht_b, h, sH, Dx);
    // BatchNorm stats + apply + residual
    bn_stats<<<Cx, blk, 0, stream>>>(h, mean, rsig);
    bn_apply<<<(Bx * Cx * Tx) / 4 / 256, blk, 0, stream>>>(
        inpt, h, mean, rsig, gamma, beta, (float*)d_out);
}

// Round 2
// 480.303 us; speedup vs baseline: 2.1989x; 2.1989x over previous
//
#include <hip/hip_runtime.h>
#include <math.h>

#define Bx 8
#define Cx 512
#define Dx 256
#define Tx 2048
#define EPSx 1e-5f

typedef _Float16 h16;
typedef __attribute__((ext_vector_type(8))) _Float16 h16x8;
typedef __attribute__((ext_vector_type(4))) float f32x4;

// ---------------------------------------------------------------------------
// f16 MFMA GEMM: C[m][n] = sum_k A[m][k]*B[n][k] (+biasM[m]) (+biasN[n])
// A: M x K row-major (k contiguous), B: N x K row-major (k contiguous),
// C: M x N row-major, f16 output. Tiles 128x128, BK=64, 256 thr = 4 waves,
// each wave 64x64 via 4x4 grid of 16x16x32 MFMA. LDS rows padded 64->72 h16.
// ---------------------------------------------------------------------------
__global__ __launch_bounds__(256, 2)
void gemm_h16(const h16* __restrict__ A, long aStr,
              const h16* __restrict__ B, long bStr,
              h16* __restrict__ C, long cStr,
              int M, int N, int K,
              const float* __restrict__ biasM,
              const float* __restrict__ biasN) {
    __shared__ h16 As[128 * 72];
    __shared__ h16 Bs[128 * 72];
    const int tid  = threadIdx.x;
    const int lane = tid & 63, wid = tid >> 6;
    const int wm = (wid & 1) * 64, wn = (wid >> 1) * 64;
    const int lm = lane & 15, quad = lane >> 4;
    const int m0 = blockIdx.y * 128, n0 = blockIdx.x * 128;
    const h16* Ab = A + (size_t)blockIdx.z * aStr + (size_t)m0 * K;
    const h16* Bb = B + (size_t)blockIdx.z * bStr + (size_t)n0 * K;
    h16* Cb = C + (size_t)blockIdx.z * cStr;

    f32x4 acc[4][4] = {};

    for (int k0 = 0; k0 < K; k0 += 64) {
        uint4 av[4], bv[4];
#pragma unroll
        for (int i = 0; i < 4; i++) {
            int idx = tid + 256 * i;
            int r = idx >> 3, c8 = idx & 7;
            av[i] = *(const uint4*)(Ab + (size_t)r * K + k0 + c8 * 8);
            bv[i] = *(const uint4*)(Bb + (size_t)r * K + k0 + c8 * 8);
        }
        __syncthreads();   // previous iteration's fragment reads done
#pragma unroll
        for (int i = 0; i < 4; i++) {
            int idx = tid + 256 * i;
            int r = idx >> 3, c8 = idx & 7;
            *(uint4*)(As + r * 72 + c8 * 8) = av[i];
            *(uint4*)(Bs + r * 72 + c8 * 8) = bv[i];
        }
        __syncthreads();
#pragma unroll
        for (int ks = 0; ks < 2; ks++) {
            h16x8 af[4], bf[4];
#pragma unroll
            for (int i = 0; i < 4; i++)
                af[i] = *(const h16x8*)(As + (wm + 16 * i + lm) * 72 + ks * 32 + quad * 8);
#pragma unroll
            for (int j = 0; j < 4; j++)
                bf[j] = *(const h16x8*)(Bs + (wn + 16 * j + lm) * 72 + ks * 32 + quad * 8);
#pragma unroll
            for (int i = 0; i < 4; i++)
#pragma unroll
                for (int j = 0; j < 4; j++)
                    acc[i][j] = __builtin_amdgcn_mfma_f32_16x16x32_f16(
                        af[i], bf[j], acc[i][j], 0, 0, 0);
        }
    }
    // epilogue: C/D layout col=lane&15, row=quad*4+reg
#pragma unroll
    for (int i = 0; i < 4; i++) {
#pragma unroll
        for (int j = 0; j < 4; j++) {
            int row = m0 + wm + 16 * i + quad * 4;
            int col = n0 + wn + 16 * j + lm;
            float bN = biasN ? biasN[col] : 0.0f;
#pragma unroll
            for (int r = 0; r < 4; r++) {
                float v = acc[i][j][r] + bN;
                if (biasM) v += biasM[row + r];
                Cb[(size_t)(row + r) * N + col] = (h16)v;
            }
        }
    }
}

// ---------------------------------------------------------------------------
// inpt[b][c][t] fp32 -> xT[b][t][c] f16 via 64x64 LDS tile transpose.
// ---------------------------------------------------------------------------
__global__ __launch_bounds__(256)
void conv_x(const float* __restrict__ inpt, h16* __restrict__ xT) {
    __shared__ float lds[64][68];   // [c][t]
    const int b = blockIdx.z;
    const int t0 = blockIdx.x * 64, c0 = blockIdx.y * 64;
    const int tid = threadIdx.x, q = tid >> 4, k = tid & 15;
    const float* ib = inpt + (size_t)b * Cx * Tx;
#pragma unroll
    for (int i = 0; i < 4; i++) {
        int c = q + 16 * i;
        float4 v = *(const float4*)(ib + (size_t)(c0 + c) * Tx + t0 + 4 * k);
        *(float4*)&lds[c][4 * k] = v;
    }
    __syncthreads();
    h16* xb = xT + (size_t)b * Tx * Cx;
#pragma unroll
    for (int i = 0; i < 4; i++) {
        int t = q + 16 * i;
        h16 o[4];
#pragma unroll
        for (int j = 0; j < 4; j++) o[j] = (h16)lds[4 * k + j][t];
        *(uint2*)(xb + (size_t)(t0 + t) * Cx + c0 + 4 * k) = *(uint2*)o;
    }
}

// ---------------------------------------------------------------------------
// 4 weight arrays (131072 fp32 each) -> f16, concatenated.
// ---------------------------------------------------------------------------
__global__ __launch_bounds__(256)
void conv_w(const float* __restrict__ w0, const float* __restrict__ w1,
            const float* __restrict__ w2, const float* __restrict__ w3,
            h16* __restrict__ dst) {
    int idx4 = blockIdx.x * 256 + threadIdx.x;   // float4 index, 131072 total
    int arr = idx4 >> 15, local4 = idx4 & 32767;
    const float* srcs[4] = {w0, w1, w2, w3};
    float4 v = ((const float4*)srcs[arr])[local4];
    h16 o[4] = {(h16)v.x, (h16)v.y, (h16)v.z, (h16)v.w};
    *(uint2*)(dst + (size_t)arr * 131072 + (size_t)local4 * 4) = *(uint2*)o;
}

// ---------------------------------------------------------------------------
// Pass 1: per-row (t) max and 1/sum(exp) over s.  One block per row.
// ---------------------------------------------------------------------------
__global__ __launch_bounds__(256)
void softmax_stat(const h16* __restrict__ L, float2* __restrict__ rowms) {
    const h16* row = L + (size_t)blockIdx.x * Tx;
    const int tid = threadIdx.x;
    uint4 v = ((const uint4*)row)[tid];
    const h16* hp = (const h16*)&v;
    float x[8];
    float mx = -3.0e38f;
#pragma unroll
    for (int i = 0; i < 8; i++) { x[i] = (float)hp[i]; mx = fmaxf(mx, x[i]); }
#pragma unroll
    for (int off = 32; off; off >>= 1) mx = fmaxf(mx, __shfl_xor(mx, off));
    __shared__ float redm[4], reds[4];
    if ((tid & 63) == 0) redm[tid >> 6] = mx;
    __syncthreads();
    mx = fmaxf(fmaxf(redm[0], redm[1]), fmaxf(redm[2], redm[3]));
    float s = 0.0f;
#pragma unroll
    for (int i = 0; i < 8; i++) s += __expf(x[i] - mx);
#pragma unroll
    for (int off = 32; off; off >>= 1) s += __shfl_xor(s, off);
    if ((tid & 63) == 0) reds[tid >> 6] = s;
    __syncthreads();
    if (tid == 0) {
        s = reds[0] + reds[1] + reds[2] + reds[3];
        rowms[blockIdx.x] = make_float2(mx, 1.0f / s);
    }
}

// ---------------------------------------------------------------------------
// Pass 2: W[t][s] = exp(L-m)/sum, written TRANSPOSED as WT[b][s][t] f16.
// ---------------------------------------------------------------------------
__global__ __launch_bounds__(256)
void softmax_norm_T(const h16* __restrict__ L, const float2* __restrict__ rowms,
                    h16* __restrict__ WT) {
    __shared__ float lds[64][68];   // [t][s]
    const int b = blockIdx.z;
    const int s0 = blockIdx.x * 64, t0 = blockIdx.y * 64;
    const int tid = threadIdx.x, q = tid >> 4, k = tid & 15;
    const h16* Lb = L + (size_t)b * Tx * Tx;
    h16* Wb = WT + (size_t)b * Tx * Tx;
#pragma unroll
    for (int i = 0; i < 4; i++) {
        int t = q + 16 * i;
        float2 ms = rowms[(size_t)b * Tx + t0 + t];
        uint2 raw = *(const uint2*)(Lb + (size_t)(t0 + t) * Tx + s0 + 4 * k);
        const h16* hp = (const h16*)&raw;
        float4 w;
        w.x = __expf((float)hp[0] - ms.x) * ms.y;
        w.y = __expf((float)hp[1] - ms.x) * ms.y;
        w.z = __expf((float)hp[2] - ms.x) * ms.y;
        w.w = __expf((float)hp[3] - ms.x) * ms.y;
        *(float4*)&lds[t][4 * k] = w;
    }
    __syncthreads();
#pragma unroll
    for (int i = 0; i < 4; i++) {
        int s = q + 16 * i;
        h16 o[4];
#pragma unroll
        for (int j = 0; j < 4; j++) o[j] = (h16)lds[4 * k + j][s];
        *(uint2*)(Wb + (size_t)(s0 + s) * Tx + t0 + 4 * k) = *(uint2*)o;
    }
}

// ---------------------------------------------------------------------------
// BN partial sums: hT[b][t][c] f16 (c contiguous). Block = (b, 128-t slab);
// thread owns channels tid*2, tid*2+1.
// ---------------------------------------------------------------------------
__global__ __launch_bounds__(256)
void bn_partial(const h16* __restrict__ hT, float* __restrict__ ps,
                float* __restrict__ pss) {
    const int blk = blockIdx.x;            // b*16 + slab
    const int b = blk >> 4, slab = blk & 15;
    const int tid = threadIdx.x;
    const h16* base = hT + (size_t)b * Tx * Cx + (size_t)slab * 128 * Cx;
    float s0 = 0, ss0 = 0, s1 = 0, ss1 = 0;
    for (int r = 0; r < 128; r++) {
        uint u = *(const uint*)(base + (size_t)r * Cx + tid * 2);
        float fa = (float)((const h16*)&u)[0];
        float fc = (float)((const h16*)&u)[1];
        s0 += fa; ss0 += fa * fa;
        s1 += fc; ss1 += fc * fc;
    }
    ps [blk * Cx + tid * 2]     = s0;  pss[blk * Cx + tid * 2]     = ss0;
    ps [blk * Cx + tid * 2 + 1] = s1;  pss[blk * Cx + tid * 2 + 1] = ss1;
}

__global__ __launch_bounds__(256)
void bn_final(const float* __restrict__ ps, const float* __restrict__ pss,
              float* __restrict__ mean, float* __restrict__ rsig) {
    int c = blockIdx.x * 256 + threadIdx.x;
    float s = 0, ss = 0;
    for (int i = 0; i < 128; i++) { s += ps[i * Cx + c]; ss += pss[i * Cx + c]; }
    const float invN = 1.0f / (float)(Bx * Tx);
    float mu = s * invN;
    float var = ss * invN - mu * mu;
    mean[c] = mu;
    rsig[c] = rsqrtf(var + EPSx);
}

// ---------------------------------------------------------------------------
// out[b][c][t] = inpt + gamma[c]*(hT[b][t][c]-mu)*rsig + beta[c]
// 64x64 tile transpose of hT back to [c][t].
// ---------------------------------------------------------------------------
__global__ __launch_bounds__(256)
void bn_apply_T(const float* __restrict__ inpt, const h16* __restrict__ hT,
                const float* __restrict__ mean, const float* __restrict__ rsig,
                const float* __restrict__ gamma, const float* __restrict__ beta,
                float* __restrict__ out) {
    __shared__ float lds[64][68];   // [t][c]
    const int b = blockIdx.z, t0 = blockIdx.x * 64, c0 = blockIdx.y * 64;
    const int tid = threadIdx.x, q = tid >> 4, k = tid & 15;
    const h16* hb = hT + (size_t)b * Tx * Cx;
#pragma unroll
    for (int i = 0; i < 4; i++) {
        int t = q + 16 * i;
        uint2 raw = *(const uint2*)(hb + (size_t)(t0 + t) * Cx + c0 + 4 * k);
        const h16* hp = (const h16*)&raw;
        float4 v = make_float4((float)hp[0], (float)hp[1], (float)hp[2], (float)hp[3]);
        *(float4*)&lds[t][4 * k] = v;
    }
    __syncthreads();
    const float* ib = inpt + (size_t)b * Cx * Tx;
    float* ob = out + (size_t)b * Cx * Tx;
#pragma unroll
    for (int i = 0; i < 4; i++) {
        int c = q + 16 * i;
        int cg = c0 + c;
        float mu = mean[cg], rv = rsig[cg], ga = gamma[cg], be = beta[cg];
        float4 x = *(const float4*)(ib + (size_t)cg * Tx + t0 + 4 * k);
        float4 o;
        o.x = x.x + ga * (lds[4 * k + 0][c] - mu) * rv + be;
        o.y = x.y + ga * (lds[4 * k + 1][c] - mu) * rv + be;
        o.z = x.z + ga * (lds[4 * k + 2][c] - mu) * rv + be;
        o.w = x.w + ga * (lds[4 * k + 3][c] - mu) * rv + be;
        *(float4*)(ob + (size_t)cg * Tx + t0 + 4 * k) = o;
    }
}

// ---------------------------------------------------------------------------
// Workspace layout (byte offsets; total 177,868,800 B = 169.6 MiB):
//   xT     @0            16 MiB  (h16, [b][t][c])   -> reused as hT
//   w4     @16,777,216    1 MiB  (theta_w|phi_w|g_w|ht_w, f16)
//   thetaT @17,825,792    8 MiB  ([b][t][d])        -> reused as attnT
//   phiT   @26,214,400    8 MiB
//   g      @34,603,008    8 MiB  ([b][d][t])
//   L      @42,991,616   64 MiB  (f16 logits [b][t][s])
//   WT     @110,100,480  64 MiB  (f16 [b][s][t])
//   rowms  @177,209,344  float2[16384]
//   ps     @177,340,416  float[65536]
//   pss    @177,602,560  float[65536]
//   mean   @177,864,704  float[512]
//   rsig   @177,866,752  float[512]
// ---------------------------------------------------------------------------
extern "C" void kernel_launch(void* const* d_in, const int* in_sizes, int n_in,
                              void* d_out, int out_size, void* d_ws, size_t ws_size,
                              hipStream_t stream) {
    const float* inpt    = (const float*)d_in[0];
    const float* theta_w = (const float*)d_in[1];
    const float* theta_b = (const float*)d_in[2];
    const float* phi_w   = (const float*)d_in[3];
    const float* phi_b   = (const float*)d_in[4];
    const float* g_w     = (const float*)d_in[5];
    const float* g_b     = (const float*)d_in[6];
    const float* ht_w    = (const float*)d_in[7];
    const float* ht_b    = (const float*)d_in[8];
    const float* gamma   = (const float*)d_in[9];
    const float* beta    = (const float*)d_in[10];

    char* ws = (char*)d_ws;
    h16* xT     = (h16*)(ws + 0);
    h16* w4     = (h16*)(ws + 16777216);
    h16* wTheta = w4;
    h16* wPhi   = w4 + 131072;
    h16* wG     = w4 + 262144;
    h16* wHt    = w4 + 393216;
    h16* thetaT = (h16*)(ws + 17825792);
    h16* phiT   = (h16*)(ws + 26214400);
    h16* g      = (h16*)(ws + 34603008);
    h16* L      = (h16*)(ws + 42991616);
    h16* WT     = (h16*)(ws + 110100480);
    float2* rowms = (float2*)(ws + 177209344);
    float* ps   = (float*)(ws + 177340416);
    float* pss  = (float*)(ws + 177602560);
    float* mu   = (float*)(ws + 177864704);
    float* rs   = (float*)(ws + 177866752);
    h16* attnT  = thetaT;   // reuse (dead after logits)
    h16* hT     = xT;       // reuse (dead after projections)

    const long sX = (long)Tx * Cx;   // 1,048,576
    const long sP = (long)Tx * Dx;   //   524,288
    const long sW = (long)Tx * Tx;   // 4,194,304

    dim3 blk(256);
    // inpt -> xT (f16, transposed)
    conv_x<<<dim3(Tx / 64, Cx / 64, Bx), blk, 0, stream>>>(inpt, xT);
    // weights -> f16
    conv_w<<<512, blk, 0, stream>>>(theta_w, phi_w, g_w, ht_w, w4);
    // thetaT[t][d] = sum_c xT[t][c]*theta_w[d][c] + theta_b[d]
    gemm_h16<<<dim3(Dx / 128, Tx / 128, Bx), blk, 0, stream>>>(
        xT, sX, wTheta, 0, thetaT, sP, Tx, Dx, Cx, nullptr, theta_b);
    gemm_h16<<<dim3(Dx / 128, Tx / 128, Bx), blk, 0, stream>>>(
        xT, sX, wPhi, 0, phiT, sP, Tx, Dx, Cx, nullptr, phi_b);
    // g[d][t] = sum_c g_w[d][c]*xT[t][c] + g_b[d]
    gemm_h16<<<dim3(Tx / 128, Dx / 128, Bx), blk, 0, stream>>>(
        wG, 0, xT, sX, g, sP, Dx, Tx, Cx, g_b, nullptr);
    // L[t][s] = sum_d thetaT[t][d]*phiT[s][d]
    gemm_h16<<<dim3(Tx / 128, Tx / 128, Bx), blk, 0, stream>>>(
        thetaT, sP, phiT, sP, L, sW, Tx, Tx, Dx, nullptr, nullptr);
    // softmax over s, output transposed WT[s][t]
    softmax_stat<<<Bx * Tx, blk, 0, stream>>>(L, rowms);
    softmax_norm_T<<<dim3(Tx / 64, Tx / 64, Bx), blk, 0, stream>>>(L, rowms, WT);
    // attnT[s][d] = sum_t WT[s][t]*g[d][t]
    gemm_h16<<<dim3(Dx / 128, Tx / 128, Bx), blk, 0, stream>>>(
        WT, sW, g, sP, attnT, sP, Tx, Dx, Tx, nullptr, nullptr);
    // hT[t][c] = sum_d attnT[t][d]*ht_w[c][d] + ht_b[c]
    gemm_h16<<<dim3(Cx / 128, Tx / 128, Bx), blk, 0, stream>>>(
        attnT, sP, wHt, 0, hT, sX, Tx, Cx, Dx, nullptr, ht_b);
    // BatchNorm (training stats) + residual, transposing back to [c][t]
    bn_partial<<<Bx * 16, blk, 0, stream>>>(hT, ps, pss);
    bn_final<<<2, blk, 0, stream>>>(ps, pss, mu, rs);
    bn_apply_T<<<dim3(Tx / 64, Cx / 64, Bx), blk, 0, stream>>>(
        inpt, hT, mu, rs, gamma, beta, (float*)d_out);
}

// Round 3
// 290.015 us; speedup vs baseline: 3.6417x; 1.6561x over previous
//
#include <hip/hip_runtime.h>
#include <math.h>

#define Bx 8
#define Cx 512
#define Dx 256
#define Tx 2048
#define EPSx 1e-5f

typedef _Float16 h16;
typedef __attribute__((ext_vector_type(8))) _Float16 h16x8;
typedef __attribute__((ext_vector_type(4))) float f32x4;

typedef __attribute__((address_space(3))) unsigned int lds_u32;
typedef __attribute__((address_space(1))) const unsigned int glb_u32;

// async 16B global -> LDS DMA. ldsp must be wave-uniform; HW adds lane*16.
__device__ __forceinline__ void cp16(void* ldsp, const void* g) {
    __builtin_amdgcn_global_load_lds((glb_u32*)g, (lds_u32*)ldsp, 16, 0, 0);
}

// ---------------------------------------------------------------------------
// f16 MFMA GEMM: C[m][n] = sum_k A[m][k]*B[n][k] (+biasM[m]) (+biasN[n])
// A: M rows, row stride lda (k contiguous); B: N rows, row stride ldb.
// Tile 128x128, BK=64, 4 waves (2x2 of 64x64), 16x16x32 MFMA.
// Staging: global_load_lds 16B with XOR swizzle (chunk ^= row&7), no padding.
// If Cp != nullptr: write fp32 partials at Cp + z*M*N (split-K mode, no bias).
// ---------------------------------------------------------------------------
__global__ __launch_bounds__(256, 4)
void gemm_h16(const h16* __restrict__ A, long aBatch, int lda,
              const h16* __restrict__ B, long bBatch, int ldb,
              h16* __restrict__ C, long cBatch, int ldc,
              float* __restrict__ Cp,
              int M, int N, int K, int kSlices,
              const float* __restrict__ biasM, const float* __restrict__ biasN) {
    __shared__ h16 As[128 * 64];
    __shared__ h16 Bs[128 * 64];
    const int tid  = threadIdx.x;
    const int lane = tid & 63, wid = tid >> 6;
    const int wm = (wid & 1) * 64, wn = (wid >> 1) * 64;
    const int lm = lane & 15, quad = lane >> 4;
    const int m0 = blockIdx.y * 128, n0 = blockIdx.x * 128;
    const int z = blockIdx.z;
    const int b = z / kSlices, slice = z - b * kSlices;
    const int kPer = K / kSlices, kBeg = slice * kPer;
    const h16* Ab = A + (size_t)b * aBatch + (size_t)m0 * lda;
    const h16* Bb = B + (size_t)b * bBatch + (size_t)n0 * ldb;

    // staging map: thread covers 8 h16 at LDS linear offset i*2048 + tid*8
    const int srow  = tid >> 3;                 // row within 32-row group
    const int scst  = tid & 7;                  // stored chunk index
    const int sclog = scst ^ (srow & 7);        // logical k-chunk (XOR swizzle)
    char* ldsA = (char*)As + (tid & ~63) * 16;  // wave-uniform base
    char* ldsB = (char*)Bs + (tid & ~63) * 16;

    f32x4 acc[4][4] = {};

    for (int k0 = kBeg; k0 < kBeg + kPer; k0 += 64) {
        __syncthreads();   // all waves done reading previous tile
#pragma unroll
        for (int i = 0; i < 4; i++) {
            int r = srow + 32 * i;
            cp16(ldsA + i * 4096, Ab + (size_t)r * lda + k0 + sclog * 8);
        }
#pragma unroll
        for (int i = 0; i < 4; i++) {
            int r = srow + 32 * i;
            cp16(ldsB + i * 4096, Bb + (size_t)r * ldb + k0 + sclog * 8);
        }
        __syncthreads();   // drains vmcnt(0): tile resident
#pragma unroll
        for (int ks = 0; ks < 2; ks++) {
            h16x8 af[4], bf[4];
#pragma unroll
            for (int i = 0; i < 4; i++) {
                int row = wm + 16 * i + lm;
                int st = (ks * 4 + quad) ^ (lm & 7);
                af[i] = *(const h16x8*)(As + row * 64 + st * 8);
            }
#pragma unroll
            for (int j = 0; j < 4; j++) {
                int row = wn + 16 * j + lm;
                int st = (ks * 4 + quad) ^ (lm & 7);
                bf[j] = *(const h16x8*)(Bs + row * 64 + st * 8);
            }
#pragma unroll
            for (int i = 0; i < 4; i++)
#pragma unroll
                for (int j = 0; j < 4; j++)
                    acc[i][j] = __builtin_amdgcn_mfma_f32_16x16x32_f16(
                        af[i], bf[j], acc[i][j], 0, 0, 0);
        }
    }

    // epilogue: C/D layout col=lane&15, row=quad*4+reg
    if (Cp) {
        float* Pb = Cp + (size_t)z * M * N;
#pragma unroll
        for (int i = 0; i < 4; i++)
#pragma unroll
            for (int j = 0; j < 4; j++) {
                int row = m0 + wm + 16 * i + quad * 4;
                int col = n0 + wn + 16 * j + lm;
#pragma unroll
                for (int r = 0; r < 4; r++)
                    Pb[(size_t)(row + r) * N + col] = acc[i][j][r];
            }
    } else {
        h16* Cb = C + (size_t)b * cBatch;
#pragma unroll
        for (int i = 0; i < 4; i++)
#pragma unroll
            for (int j = 0; j < 4; j++) {
                int row = m0 + wm + 16 * i + quad * 4;
                int col = n0 + wn + 16 * j + lm;
                float bN = biasN ? biasN[col] : 0.0f;
#pragma unroll
                for (int r = 0; r < 4; r++) {
                    float v = acc[i][j][r] + bN;
                    if (biasM) v += biasM[row + r];
                    Cb[(size_t)(row + r) * ldc + col] = (h16)v;
                }
            }
    }
}

// ---------------------------------------------------------------------------
// inpt[b][c][t] fp32 -> xT[b][t][c] f16 via 64x64 LDS tile transpose.
// ---------------------------------------------------------------------------
__global__ __launch_bounds__(256)
void conv_x(const float* __restrict__ inpt, h16* __restrict__ xT) {
    __shared__ float lds[64][68];
    const int b = blockIdx.z;
    const int t0 = blockIdx.x * 64, c0 = blockIdx.y * 64;
    const int tid = threadIdx.x, q = tid >> 4, k = tid & 15;
    const float* ib = inpt + (size_t)b * Cx * Tx;
#pragma unroll
    for (int i = 0; i < 4; i++) {
        int c = q + 16 * i;
        float4 v = *(const float4*)(ib + (size_t)(c0 + c) * Tx + t0 + 4 * k);
        *(float4*)&lds[c][4 * k] = v;
    }
    __syncthreads();
    h16* xb = xT + (size_t)b * Tx * Cx;
#pragma unroll
    for (int i = 0; i < 4; i++) {
        int t = q + 16 * i;
        h16 o[4];
#pragma unroll
        for (int j = 0; j < 4; j++) o[j] = (h16)lds[4 * k + j][t];
        *(uint2*)(xb + (size_t)(t0 + t) * Cx + c0 + 4 * k) = *(uint2*)o;
    }
}

// ---------------------------------------------------------------------------
// 4 weight arrays -> f16 concat; block 512 builds bias2 = theta_b || phi_b.
// ---------------------------------------------------------------------------
__global__ __launch_bounds__(256)
void conv_w(const float* __restrict__ w0, const float* __restrict__ w1,
            const float* __restrict__ w2, const float* __restrict__ w3,
            const float* __restrict__ tb, const float* __restrict__ pb,
            h16* __restrict__ dst, float* __restrict__ bias2) {
    if (blockIdx.x == 512) {
        int i = threadIdx.x;
        bias2[i] = tb[i];
        bias2[i + 256] = pb[i];
        return;
    }
    int idx4 = blockIdx.x * 256 + threadIdx.x;
    int arr = idx4 >> 15, local4 = idx4 & 32767;
    const float* srcs[4] = {w0, w1, w2, w3};
    float4 v = ((const float4*)srcs[arr])[local4];
    h16 o[4] = {(h16)v.x, (h16)v.y, (h16)v.z, (h16)v.w};
    *(uint2*)(dst + (size_t)arr * 131072 + (size_t)local4 * 4) = *(uint2*)o;
}

// ---------------------------------------------------------------------------
// Softmax pass 1: per-row max and 1/sum(exp).
// ---------------------------------------------------------------------------
__global__ __launch_bounds__(256)
void softmax_stat(const h16* __restrict__ L, float2* __restrict__ rowms) {
    const h16* row = L + (size_t)blockIdx.x * Tx;
    const int tid = threadIdx.x;
    uint4 v = ((const uint4*)row)[tid];
    const h16* hp = (const h16*)&v;
    float x[8];
    float mx = -3.0e38f;
#pragma unroll
    for (int i = 0; i < 8; i++) { x[i] = (float)hp[i]; mx = fmaxf(mx, x[i]); }
#pragma unroll
    for (int off = 32; off; off >>= 1) mx = fmaxf(mx, __shfl_xor(mx, off));
    __shared__ float redm[4], reds[4];
    if ((tid & 63) == 0) redm[tid >> 6] = mx;
    __syncthreads();
    mx = fmaxf(fmaxf(redm[0], redm[1]), fmaxf(redm[2], redm[3]));
    float s = 0.0f;
#pragma unroll
    for (int i = 0; i < 8; i++) s += __expf(x[i] - mx);
#pragma unroll
    for (int off = 32; off; off >>= 1) s += __shfl_xor(s, off);
    if ((tid & 63) == 0) reds[tid >> 6] = s;
    __syncthreads();
    if (tid == 0) {
        s = reds[0] + reds[1] + reds[2] + reds[3];
        rowms[blockIdx.x] = make_float2(mx, 1.0f / s);
    }
}

// ---------------------------------------------------------------------------
// Softmax pass 2: normalize + transpose -> WT[b][s][t] f16.
// ---------------------------------------------------------------------------
__global__ __launch_bounds__(256)
void softmax_norm_T(const h16* __restrict__ L, const float2* __restrict__ rowms,
                    h16* __restrict__ WT) {
    __shared__ float lds[64][68];
    const int b = blockIdx.z;
    const int s0 = blockIdx.x * 64, t0 = blockIdx.y * 64;
    const int tid = threadIdx.x, q = tid >> 4, k = tid & 15;
    const h16* Lb = L + (size_t)b * Tx * Tx;
    h16* Wb = WT + (size_t)b * Tx * Tx;
#pragma unroll
    for (int i = 0; i < 4; i++) {
        int t = q + 16 * i;
        float2 ms = rowms[(size_t)b * Tx + t0 + t];
        uint2 raw = *(const uint2*)(Lb + (size_t)(t0 + t) * Tx + s0 + 4 * k);
        const h16* hp = (const h16*)&raw;
        float4 w;
        w.x = __expf((float)hp[0] - ms.x) * ms.y;
        w.y = __expf((float)hp[1] - ms.x) * ms.y;
        w.z = __expf((float)hp[2] - ms.x) * ms.y;
        w.w = __expf((float)hp[3] - ms.x) * ms.y;
        *(float4*)&lds[t][4 * k] = w;
    }
    __syncthreads();
#pragma unroll
    for (int i = 0; i < 4; i++) {
        int s = q + 16 * i;
        h16 o[4];
#pragma unroll
        for (int j = 0; j < 4; j++) o[j] = (h16)lds[4 * k + j][s];
        *(uint2*)(Wb + (size_t)(s0 + s) * Tx + t0 + 4 * k) = *(uint2*)o;
    }
}

// ---------------------------------------------------------------------------
// Split-K reduce: attnT[b][r] = sum over 4 fp32 partial slices, cast f16.
// ---------------------------------------------------------------------------
__global__ __launch_bounds__(256)
void reduce4(const float* __restrict__ P, h16* __restrict__ attnT) {
    int idx4 = blockIdx.x * 256 + threadIdx.x;       // float4 units
    int b = idx4 >> 17, r = idx4 & 131071;
    const float* base = P + (size_t)b * 2097152 + (size_t)r * 4;
    float4 s = *(const float4*)(base);
#pragma unroll
    for (int sl = 1; sl < 4; sl++) {
        float4 v = *(const float4*)(base + (size_t)sl * 524288);
        s.x += v.x; s.y += v.y; s.z += v.z; s.w += v.w;
    }
    h16 o[4] = {(h16)s.x, (h16)s.y, (h16)s.z, (h16)s.w};
    *(uint2*)(attnT + (size_t)b * 524288 + (size_t)r * 4) = *(uint2*)o;
}

// ---------------------------------------------------------------------------
// BN partial sums over 128-row t-slabs of hT[b][t][c].
// ---------------------------------------------------------------------------
__global__ __launch_bounds__(256)
void bn_partial(const h16* __restrict__ hT, float* __restrict__ ps,
                float* __restrict__ pss) {
    const int blk = blockIdx.x;
    const int b = blk >> 4, slab = blk & 15;
    const int tid = threadIdx.x;
    const h16* base = hT + (size_t)b * Tx * Cx + (size_t)slab * 128 * Cx;
    float s0 = 0, ss0 = 0, s1 = 0, ss1 = 0;
    for (int r = 0; r < 128; r++) {
        uint u = *(const uint*)(base + (size_t)r * Cx + tid * 2);
        float fa = (float)((const h16*)&u)[0];
        float fc = (float)((const h16*)&u)[1];
        s0 += fa; ss0 += fa * fa;
        s1 += fc; ss1 += fc * fc;
    }
    ps [blk * Cx + tid * 2]     = s0;  pss[blk * Cx + tid * 2]     = ss0;
    ps [blk * Cx + tid * 2 + 1] = s1;  pss[blk * Cx + tid * 2 + 1] = ss1;
}

__global__ __launch_bounds__(256)
void bn_final(const float* __restrict__ ps, const float* __restrict__ pss,
              float* __restrict__ mean, float* __restrict__ rsig) {
    int c = blockIdx.x * 256 + threadIdx.x;
    float s = 0, ss = 0;
    for (int i = 0; i < 128; i++) { s += ps[i * Cx + c]; ss += pss[i * Cx + c]; }
    const float invN = 1.0f / (float)(Bx * Tx);
    float mu = s * invN;
    float var = ss * invN - mu * mu;
    mean[c] = mu;
    rsig[c] = rsqrtf(var + EPSx);
}

// ---------------------------------------------------------------------------
// out[b][c][t] = inpt + gamma[c]*(hT[b][t][c]-mu)*rsig + beta[c]
// ---------------------------------------------------------------------------
__global__ __launch_bounds__(256)
void bn_apply_T(const float* __restrict__ inpt, const h16* __restrict__ hT,
                const float* __restrict__ mean, const float* __restrict__ rsig,
                const float* __restrict__ gamma, const float* __restrict__ beta,
                float* __restrict__ out) {
    __shared__ float lds[64][68];
    const int b = blockIdx.z, t0 = blockIdx.x * 64, c0 = blockIdx.y * 64;
    const int tid = threadIdx.x, q = tid >> 4, k = tid & 15;
    const h16* hb = hT + (size_t)b * Tx * Cx;
#pragma unroll
    for (int i = 0; i < 4; i++) {
        int t = q + 16 * i;
        uint2 raw = *(const uint2*)(hb + (size_t)(t0 + t) * Cx + c0 + 4 * k);
        const h16* hp = (const h16*)&raw;
        float4 v = make_float4((float)hp[0], (float)hp[1], (float)hp[2], (float)hp[3]);
        *(float4*)&lds[t][4 * k] = v;
    }
    __syncthreads();
    const float* ib = inpt + (size_t)b * Cx * Tx;
    float* ob = out + (size_t)b * Cx * Tx;
#pragma unroll
    for (int i = 0; i < 4; i++) {
        int c = q + 16 * i;
        int cg = c0 + c;
        float mu = mean[cg], rv = rsig[cg], ga = gamma[cg], be = beta[cg];
        float4 x = *(const float4*)(ib + (size_t)cg * Tx + t0 + 4 * k);
        float4 o;
        o.x = x.x + ga * (lds[4 * k + 0][c] - mu) * rv + be;
        o.y = x.y + ga * (lds[4 * k + 1][c] - mu) * rv + be;
        o.z = x.z + ga * (lds[4 * k + 2][c] - mu) * rv + be;
        o.w = x.w + ga * (lds[4 * k + 3][c] - mu) * rv + be;
        *(float4*)(ob + (size_t)cg * Tx + t0 + 4 * k) = o;
    }
}

// ---------------------------------------------------------------------------
// Workspace (bytes, total ~169.6 MiB):
//   xT    @0           16,777,216  (-> hT)
//   w4    @16,777,216   1,048,576  (theta|phi|g|ht f16)
//   bias2 @17,825,792       2,048
//   thph  @17,827,840  16,777,216  ([b][t][0:256]=theta,[256:512]=phi -> attnT)
//   g     @34,605,056   8,388,608  ([b][d][t])
//   L     @42,993,664  67,108,864  (f16 logits; later fp32 split-K partials)
//   WT    @110,102,528 67,108,864  ([b][s][t])
//   rowms @177,211,392    131,072
//   ps    @177,342,464    262,144
//   pss   @177,604,608    262,144
//   mean  @177,866,752      2,048
//   rsig  @177,868,800      2,048
// ---------------------------------------------------------------------------
extern "C" void kernel_launch(void* const* d_in, const int* in_sizes, int n_in,
                              void* d_out, int out_size, void* d_ws, size_t ws_size,
                              hipStream_t stream) {
    const float* inpt    = (const float*)d_in[0];
    const float* theta_w = (const float*)d_in[1];
    const float* theta_b = (const float*)d_in[2];
    const float* phi_w   = (const float*)d_in[3];
    const float* phi_b   = (const float*)d_in[4];
    const float* g_w     = (const float*)d_in[5];
    const float* g_b     = (const float*)d_in[6];
    const float* ht_w    = (const float*)d_in[7];
    const float* ht_b    = (const float*)d_in[8];
    const float* gamma   = (const float*)d_in[9];
    const float* beta    = (const float*)d_in[10];

    char* ws = (char*)d_ws;
    h16*   xT    = (h16*)(ws + 0);
    h16*   w4    = (h16*)(ws + 16777216);
    h16*   wG    = w4 + 262144;
    h16*   wHt   = w4 + 393216;
    float* bias2 = (float*)(ws + 17825792);
    h16*   thph  = (h16*)(ws + 17827840);
    h16*   g     = (h16*)(ws + 34605056);
    h16*   L     = (h16*)(ws + 42993664);
    h16*   WT    = (h16*)(ws + 110102528);
    float2* rowms = (float2*)(ws + 177211392);
    float* ps    = (float*)(ws + 177342464);
    float* pss   = (float*)(ws + 177604608);
    float* mu    = (float*)(ws + 177866752);
    float* rs    = (float*)(ws + 177868800);
    h16*   attnT = thph;          // reuse: thph dead after logits
    h16*   hT    = xT;            // reuse: xT dead after projections
    float* Pf32  = (float*)L;     // reuse: L dead after softmax_norm_T

    const long sX = (long)Tx * Cx;   // 1,048,576 (xT, thph, hT batch stride)
    const long sP = (long)Tx * Dx;   //   524,288 (attnT batch stride)
    const long sW = (long)Tx * Tx;   // 4,194,304 (L, WT batch stride)

    dim3 blk(256);
    conv_x<<<dim3(Tx / 64, Cx / 64, Bx), blk, 0, stream>>>(inpt, xT);
    conv_w<<<513, blk, 0, stream>>>(theta_w, phi_w, g_w, ht_w,
                                    theta_b, phi_b, w4, bias2);
    // thph[t][n] = sum_c xT[t][c] * (theta_w||phi_w)[n][c] + bias2[n]
    gemm_h16<<<dim3(4, 16, Bx), blk, 0, stream>>>(
        xT, sX, Cx, w4, 0, Cx, thph, sX, 512, nullptr,
        Tx, 512, Cx, 1, nullptr, bias2);
    // g[d][t] = sum_c g_w[d][c] * xT[t][c] + g_b[d]
    gemm_h16<<<dim3(16, 2, Bx), blk, 0, stream>>>(
        wG, 0, Cx, xT, sX, Cx, g, sP, Tx, nullptr,
        Dx, Tx, Cx, 1, g_b, nullptr);
    // L[t][s] = sum_d theta[t][d] * phi[s][d]
    gemm_h16<<<dim3(16, 16, Bx), blk, 0, stream>>>(
        thph, sX, 512, thph + 256, sX, 512, L, sW, Tx, nullptr,
        Tx, Tx, Dx, 1, nullptr, nullptr);
    softmax_stat<<<Bx * Tx, blk, 0, stream>>>(L, rowms);
    softmax_norm_T<<<dim3(Tx / 64, Tx / 64, Bx), blk, 0, stream>>>(L, rowms, WT);
    // attnT[s][d] = sum_t WT[s][t] * g[d][t]  (split-K x4, fp32 partials in L)
    gemm_h16<<<dim3(2, 16, Bx * 4), blk, 0, stream>>>(
        WT, sW, Tx, g, sP, Tx, nullptr, 0, Dx, Pf32,
        Tx, Dx, Tx, 4, nullptr, nullptr);
    reduce4<<<4096, blk, 0, stream>>>(Pf32, attnT);
    // hT[t][c] = sum_d attnT[t][d] * ht_w[c][d] + ht_b[c]
    gemm_h16<<<dim3(4, 16, Bx), blk, 0, stream>>>(
        attnT, sP, Dx, wHt, 0, Dx, hT, sX, Cx, nullptr,
        Tx, Cx, Dx, 1, nullptr, ht_b);
    bn_partial<<<Bx * 16, blk, 0, stream>>>(hT, ps, pss);
    bn_final<<<2, blk, 0, stream>>>(ps, pss, mu, rs);
    bn_apply_T<<<dim3(Tx / 64, Cx / 64, Bx), blk, 0, stream>>>(
        inpt, hT, mu, rs, gamma, beta, (float*)d_out);
}

// Round 4
// 257.526 us; speedup vs baseline: 4.1011x; 1.1262x over previous
//
#include <hip/hip_runtime.h>
#include <hip/hip_bf16.h>
#include <math.h>

#define Bx 8
#define Cx 512
#define Dx 256
#define Tx 2048
#define EPSx 1e-5f

typedef _Float16 h16;
typedef __attribute__((ext_vector_type(8))) _Float16 h16x8;
typedef __attribute__((ext_vector_type(8))) short s16x8;
typedef __attribute__((ext_vector_type(4))) float f32x4;

typedef __attribute__((address_space(3))) unsigned int lds_u32;
typedef __attribute__((address_space(1))) const unsigned int glb_u32;

// async 16B global -> LDS DMA. ldsp must be wave-uniform; HW adds lane*16.
__device__ __forceinline__ void cp16(void* ldsp, const void* g) {
    __builtin_amdgcn_global_load_lds((glb_u32*)g, (lds_u32*)ldsp, 16, 0, 0);
}

// ---------------------------------------------------------------------------
// MFMA GEMM core: acc[m][n] = sum_k A[m][k]*B[n][k], 2-byte dtypes (f16/bf16),
// tile 128x128, BK=64, 4 waves (2x2 of 64x64), global_load_lds staging with
// XOR swizzle. Epilogue by MODE:
//   0: f16 out,  + optional biasM[row] + biasN[col]
//   1: bf16 out, (acc + biasM[row]) * (1/Z[b*N+col])          (g' = g/Z)
//   2: bf16 out = exp(acc); atomicAdd Z[b*N+col] += sum_rows  (logits)
//   3: fp32 partials at Cp + z*M*N (split-K, kSlices slices per batch)
// ---------------------------------------------------------------------------
template<int MODE, bool BF>
__global__ __launch_bounds__(256, 4)
void gemm_mf(const h16* __restrict__ A, long aBatch, int lda,
             const h16* __restrict__ B, long bBatch, int ldb,
             void* __restrict__ C, long cBatch, int ldc,
             float* __restrict__ Cp, float* __restrict__ Z,
             int M, int N, int K, int kSlices,
             const float* __restrict__ biasM, const float* __restrict__ biasN) {
    __shared__ h16 As[128 * 64];
    __shared__ h16 Bs[128 * 64];
    const int tid  = threadIdx.x;
    const int lane = tid & 63, wid = tid >> 6;
    const int wm = (wid & 1) * 64, wn = (wid >> 1) * 64;
    const int lm = lane & 15, quad = lane >> 4;
    const int m0 = blockIdx.y * 128, n0 = blockIdx.x * 128;
    const int z = blockIdx.z;
    const int b = z / kSlices, slice = z - b * kSlices;
    const int kPer = K / kSlices, kBeg = slice * kPer;
    const h16* Ab = A + (size_t)b * aBatch + (size_t)m0 * lda;
    const h16* Bb = B + (size_t)b * bBatch + (size_t)n0 * ldb;

    const int srow  = tid >> 3;                 // row within 32-row group
    const int scst  = tid & 7;                  // stored chunk index
    const int sclog = scst ^ (srow & 7);        // logical k-chunk (XOR swizzle)
    char* ldsA = (char*)As + (tid & ~63) * 16;  // wave-uniform base
    char* ldsB = (char*)Bs + (tid & ~63) * 16;

    f32x4 acc[4][4] = {};

    for (int k0 = kBeg; k0 < kBeg + kPer; k0 += 64) {
        __syncthreads();   // all waves done reading previous tile
#pragma unroll
        for (int i = 0; i < 4; i++) {
            int r = srow + 32 * i;
            cp16(ldsA + i * 4096, Ab + (size_t)r * lda + k0 + sclog * 8);
        }
#pragma unroll
        for (int i = 0; i < 4; i++) {
            int r = srow + 32 * i;
            cp16(ldsB + i * 4096, Bb + (size_t)r * ldb + k0 + sclog * 8);
        }
        __syncthreads();   // drains vmcnt(0): tile resident
#pragma unroll
        for (int ks = 0; ks < 2; ks++) {
            s16x8 af[4], bf4[4];
#pragma unroll
            for (int i = 0; i < 4; i++) {
                int row = wm + 16 * i + lm;
                int st = (ks * 4 + quad) ^ (lm & 7);
                af[i] = *(const s16x8*)(As + row * 64 + st * 8);
            }
#pragma unroll
            for (int j = 0; j < 4; j++) {
                int row = wn + 16 * j + lm;
                int st = (ks * 4 + quad) ^ (lm & 7);
                bf4[j] = *(const s16x8*)(Bs + row * 64 + st * 8);
            }
#pragma unroll
            for (int i = 0; i < 4; i++)
#pragma unroll
                for (int j = 0; j < 4; j++) {
                    if constexpr (BF)
                        acc[i][j] = __builtin_amdgcn_mfma_f32_16x16x32_bf16(
                            af[i], bf4[j], acc[i][j], 0, 0, 0);
                    else
                        acc[i][j] = __builtin_amdgcn_mfma_f32_16x16x32_f16(
                            __builtin_bit_cast(h16x8, af[i]),
                            __builtin_bit_cast(h16x8, bf4[j]), acc[i][j], 0, 0, 0);
                }
        }
    }

    // epilogue: C/D layout col=lane&15, row=quad*4+reg
    if constexpr (MODE == 0) {
        h16* Cb = (h16*)C + (size_t)b * cBatch;
#pragma unroll
        for (int i = 0; i < 4; i++)
#pragma unroll
            for (int j = 0; j < 4; j++) {
                int row = m0 + wm + 16 * i + quad * 4;
                int col = n0 + wn + 16 * j + lm;
                float bN = biasN ? biasN[col] : 0.0f;
#pragma unroll
                for (int r = 0; r < 4; r++) {
                    float v = acc[i][j][r] + bN;
                    if (biasM) v += biasM[row + r];
                    Cb[(size_t)(row + r) * ldc + col] = (h16)v;
                }
            }
    } else if constexpr (MODE == 1) {
        __hip_bfloat16* Cb = (__hip_bfloat16*)C + (size_t)b * cBatch;
#pragma unroll
        for (int j = 0; j < 4; j++) {
            int col = n0 + wn + 16 * j + lm;
            float iz = 1.0f / Z[(size_t)b * N + col];
#pragma unroll
            for (int i = 0; i < 4; i++) {
                int row = m0 + wm + 16 * i + quad * 4;
#pragma unroll
                for (int r = 0; r < 4; r++) {
                    float v = acc[i][j][r] + (biasM ? biasM[row + r] : 0.0f);
                    Cb[(size_t)(row + r) * ldc + col] = __float2bfloat16(v * iz);
                }
            }
        }
    } else if constexpr (MODE == 2) {
        __syncthreads();                       // done with As fragments
        float* Zl = (float*)As;
        if (tid < 128) Zl[tid] = 0.0f;
        __syncthreads();
        __hip_bfloat16* Cb = (__hip_bfloat16*)C + (size_t)b * cBatch;
#pragma unroll
        for (int j = 0; j < 4; j++) {
            int cl = wn + 16 * j + lm;
            int col = n0 + cl;
            float zp = 0.0f;
#pragma unroll
            for (int i = 0; i < 4; i++) {
                int row = m0 + wm + 16 * i + quad * 4;
#pragma unroll
                for (int r = 0; r < 4; r++) {
                    float e = __expf(acc[i][j][r]);
                    zp += e;
                    Cb[(size_t)(row + r) * ldc + col] = __float2bfloat16(e);
                }
            }
            atomicAdd(&Zl[cl], zp);
        }
        __syncthreads();
        if (tid < 128) atomicAdd(&Z[(size_t)b * N + n0 + tid], Zl[tid]);
    } else {  // MODE 3: fp32 split-K partials
        float* Pb = Cp + (size_t)z * M * N;
#pragma unroll
        for (int i = 0; i < 4; i++)
#pragma unroll
            for (int j = 0; j < 4; j++) {
                int row = m0 + wm + 16 * i + quad * 4;
                int col = n0 + wn + 16 * j + lm;
#pragma unroll
                for (int r = 0; r < 4; r++)
                    Pb[(size_t)(row + r) * N + col] = acc[i][j][r];
            }
    }
}

// ---------------------------------------------------------------------------
// inpt[b][c][t] fp32 -> xT[b][t][c] f16 via 64x64 LDS tile transpose.
// ---------------------------------------------------------------------------
__global__ __launch_bounds__(256)
void conv_x(const float* __restrict__ inpt, h16* __restrict__ xT) {
    __shared__ float lds[64][68];
    const int b = blockIdx.z;
    const int t0 = blockIdx.x * 64, c0 = blockIdx.y * 64;
    const int tid = threadIdx.x, q = tid >> 4, k = tid & 15;
    const float* ib = inpt + (size_t)b * Cx * Tx;
#pragma unroll
    for (int i = 0; i < 4; i++) {
        int c = q + 16 * i;
        float4 v = *(const float4*)(ib + (size_t)(c0 + c) * Tx + t0 + 4 * k);
        *(float4*)&lds[c][4 * k] = v;
    }
    __syncthreads();
    h16* xb = xT + (size_t)b * Tx * Cx;
#pragma unroll
    for (int i = 0; i < 4; i++) {
        int t = q + 16 * i;
        h16 o[4];
#pragma unroll
        for (int j = 0; j < 4; j++) o[j] = (h16)lds[4 * k + j][t];
        *(uint2*)(xb + (size_t)(t0 + t) * Cx + c0 + 4 * k) = *(uint2*)o;
    }
}

// ---------------------------------------------------------------------------
// Weights -> f16 concat; block 512: bias2 = theta_b||phi_b; blocks 513+: Z=0.
// ---------------------------------------------------------------------------
__global__ __launch_bounds__(256)
void conv_w(const float* __restrict__ w0, const float* __restrict__ w1,
            const float* __restrict__ w2, const float* __restrict__ w3,
            const float* __restrict__ tb, const float* __restrict__ pb,
            h16* __restrict__ dst, float* __restrict__ bias2,
            float* __restrict__ Z) {
    int bx = blockIdx.x;
    if (bx >= 513) { Z[(bx - 513) * 256 + threadIdx.x] = 0.0f; return; }
    if (bx == 512) {
        int i = threadIdx.x;
        bias2[i] = tb[i];
        bias2[i + 256] = pb[i];
        return;
    }
    int idx4 = bx * 256 + threadIdx.x;
    int arr = idx4 >> 15, local4 = idx4 & 32767;
    const float* srcs[4] = {w0, w1, w2, w3};
    float4 v = ((const float4*)srcs[arr])[local4];
    h16 o[4] = {(h16)v.x, (h16)v.y, (h16)v.z, (h16)v.w};
    *(uint2*)(dst + (size_t)arr * 131072 + (size_t)local4 * 4) = *(uint2*)o;
}

// ---------------------------------------------------------------------------
// Split-K reduce: attnT[b][r] = sum over 4 fp32 partial slices, cast f16.
// ---------------------------------------------------------------------------
__global__ __launch_bounds__(256)
void reduce4(const float* __restrict__ P, h16* __restrict__ attnT) {
    int idx4 = blockIdx.x * 256 + threadIdx.x;       // float4 units
    int b = idx4 >> 17, r = idx4 & 131071;
    const float* base = P + (size_t)b * 2097152 + (size_t)r * 4;
    float4 s = *(const float4*)(base);
#pragma unroll
    for (int sl = 1; sl < 4; sl++) {
        float4 v = *(const float4*)(base + (size_t)sl * 524288);
        s.x += v.x; s.y += v.y; s.z += v.z; s.w += v.w;
    }
    h16 o[4] = {(h16)s.x, (h16)s.y, (h16)s.z, (h16)s.w};
    *(uint2*)(attnT + (size_t)b * 524288 + (size_t)r * 4) = *(uint2*)o;
}

// ---------------------------------------------------------------------------
// BN partial sums over 128-row t-slabs of hT[b][t][c].
// ---------------------------------------------------------------------------
__global__ __launch_bounds__(256)
void bn_partial(const h16* __restrict__ hT, float* __restrict__ ps,
                float* __restrict__ pss) {
    const int blk = blockIdx.x;
    const int b = blk >> 4, slab = blk & 15;
    const int tid = threadIdx.x;
    const h16* base = hT + (size_t)b * Tx * Cx + (size_t)slab * 128 * Cx;
    float s0 = 0, ss0 = 0, s1 = 0, ss1 = 0;
    for (int r = 0; r < 128; r++) {
        uint u = *(const uint*)(base + (size_t)r * Cx + tid * 2);
        float fa = (float)((const h16*)&u)[0];
        float fc = (float)((const h16*)&u)[1];
        s0 += fa; ss0 += fa * fa;
        s1 += fc; ss1 += fc * fc;
    }
    ps [blk * Cx + tid * 2]     = s0;  pss[blk * Cx + tid * 2]     = ss0;
    ps [blk * Cx + tid * 2 + 1] = s1;  pss[blk * Cx + tid * 2 + 1] = ss1;
}

__global__ __launch_bounds__(256)
void bn_final(const float* __restrict__ ps, const float* __restrict__ pss,
              float* __restrict__ mean, float* __restrict__ rsig) {
    int c = blockIdx.x * 256 + threadIdx.x;
    float s = 0, ss = 0;
    for (int i = 0; i < 128; i++) { s += ps[i * Cx + c]; ss += pss[i * Cx + c]; }
    const float invN = 1.0f / (float)(Bx * Tx);
    float mu = s * invN;
    float var = ss * invN - mu * mu;
    mean[c] = mu;
    rsig[c] = rsqrtf(var + EPSx);
}

// ---------------------------------------------------------------------------
// out[b][c][t] = inpt + gamma[c]*(hT[b][t][c]-mu)*rsig + beta[c]
// ---------------------------------------------------------------------------
__global__ __launch_bounds__(256)
void bn_apply_T(const float* __restrict__ inpt, const h16* __restrict__ hT,
                const float* __restrict__ mean, const float* __restrict__ rsig,
                const float* __restrict__ gamma, const float* __restrict__ beta,
                float* __restrict__ out) {
    __shared__ float lds[64][68];
    const int b = blockIdx.z, t0 = blockIdx.x * 64, c0 = blockIdx.y * 64;
    const int tid = threadIdx.x, q = tid >> 4, k = tid & 15;
    const h16* hb = hT + (size_t)b * Tx * Cx;
#pragma unroll
    for (int i = 0; i < 4; i++) {
        int t = q + 16 * i;
        uint2 raw = *(const uint2*)(hb + (size_t)(t0 + t) * Cx + c0 + 4 * k);
        const h16* hp = (const h16*)&raw;
        float4 v = make_float4((float)hp[0], (float)hp[1], (float)hp[2], (float)hp[3]);
        *(float4*)&lds[t][4 * k] = v;
    }
    __syncthreads();
    const float* ib = inpt + (size_t)b * Cx * Tx;
    float* ob = out + (size_t)b * Cx * Tx;
#pragma unroll
    for (int i = 0; i < 4; i++) {
        int c = q + 16 * i;
        int cg = c0 + c;
        float mu = mean[cg], rv = rsig[cg], ga = gamma[cg], be = beta[cg];
        float4 x = *(const float4*)(ib + (size_t)cg * Tx + t0 + 4 * k);
        float4 o;
        o.x = x.x + ga * (lds[4 * k + 0][c] - mu) * rv + be;
        o.y = x.y + ga * (lds[4 * k + 1][c] - mu) * rv + be;
        o.z = x.z + ga * (lds[4 * k + 2][c] - mu) * rv + be;
        o.w = x.w + ga * (lds[4 * k + 3][c] - mu) * rv + be;
        *(float4*)(ob + (size_t)cg * Tx + t0 + 4 * k) = o;
    }
}

// ---------------------------------------------------------------------------
// Workspace (bytes, total ~169.6 MiB):
//   xT    @0            16,777,216  (f16 [b][t][c] -> hT reuse)
//   w4    @16,777,216    1,048,576  (theta|phi|g|ht f16)
//   bias2 @17,825,792        2,048
//   Z     @17,827,840       65,536  (fp32 row-sums of exp, [b][t])
//   thph  @17,893,376   16,777,216  (f16 [b][t][theta||phi] -> attnT reuse)
//   gp    @34,670,592    8,388,608  (bf16 g' = g/Z, [b][d][t])
//   LT    @43,059,200   67,108,864  (bf16 exp-logits [b][s][t])
//   Pbuf  @110,168,064  67,108,864  (fp32 split-K partials)
//   ps    @177,276,928     262,144
//   pss   @177,539,072     262,144
//   mean  @177,801,216       2,048
//   rsig  @177,803,264       2,048
// ---------------------------------------------------------------------------
extern "C" void kernel_launch(void* const* d_in, const int* in_sizes, int n_in,
                              void* d_out, int out_size, void* d_ws, size_t ws_size,
                              hipStream_t stream) {
    const float* inpt    = (const float*)d_in[0];
    const float* theta_w = (const float*)d_in[1];
    const float* theta_b = (const float*)d_in[2];
    const float* phi_w   = (const float*)d_in[3];
    const float* phi_b   = (const float*)d_in[4];
    const float* g_w     = (const float*)d_in[5];
    const float* g_b     = (const float*)d_in[6];
    const float* ht_w    = (const float*)d_in[7];
    const float* ht_b    = (const float*)d_in[8];
    const float* gamma   = (const float*)d_in[9];
    const float* beta    = (const float*)d_in[10];

    char* ws = (char*)d_ws;
    h16*   xT    = (h16*)(ws + 0);
    h16*   w4    = (h16*)(ws + 16777216);
    h16*   wG    = w4 + 262144;
    h16*   wHt   = w4 + 393216;
    float* bias2 = (float*)(ws + 17825792);
    float* Z     = (float*)(ws + 17827840);
    h16*   thph  = (h16*)(ws + 17893376);
    h16*   gp    = (h16*)(ws + 34670592);    // bf16 bits
    h16*   LT    = (h16*)(ws + 43059200);    // bf16 bits
    float* Pf32  = (float*)(ws + 110168064);
    float* ps    = (float*)(ws + 177276928);
    float* pss   = (float*)(ws + 177539072);
    float* mu    = (float*)(ws + 177801216);
    float* rs    = (float*)(ws + 177803264);
    h16*   attnT = thph;          // reuse: thph dead after logits
    h16*   hT    = xT;            // reuse: xT dead after g GEMM

    const long sX = (long)Tx * Cx;   // 1,048,576
    const long sP = (long)Tx * Dx;   //   524,288
    const long sW = (long)Tx * Tx;   // 4,194,304

    dim3 blk(256);
    conv_x<<<dim3(Tx / 64, Cx / 64, Bx), blk, 0, stream>>>(inpt, xT);
    conv_w<<<577, blk, 0, stream>>>(theta_w, phi_w, g_w, ht_w,
                                    theta_b, phi_b, w4, bias2, Z);
    // thph[t][n] = sum_c xT[t][c]*(theta||phi)[n][c] + bias2[n]   (f16)
    gemm_mf<0, false><<<dim3(4, 16, Bx), blk, 0, stream>>>(
        xT, sX, Cx, w4, 0, Cx, thph, sX, 512, nullptr, nullptr,
        Tx, 512, Cx, 1, nullptr, bias2);
    // LT[s][t] = exp(sum_d phi[s][d]*theta[t][d]) bf16; Z[t] += col sums
    gemm_mf<2, false><<<dim3(16, 16, Bx), blk, 0, stream>>>(
        thph + 256, sX, 512, thph, sX, 512, LT, sW, Tx, nullptr, Z,
        Tx, Tx, Dx, 1, nullptr, nullptr);
    // g'[d][t] = (sum_c g_w[d][c]*xT[t][c] + g_b[d]) / Z[t]   (bf16)
    gemm_mf<1, false><<<dim3(16, 2, Bx), blk, 0, stream>>>(
        wG, 0, Cx, xT, sX, Cx, gp, sP, Tx, nullptr, Z,
        Dx, Tx, Cx, 1, g_b, nullptr);
    // attnT[s][d] = sum_t LT[s][t]*g'[d][t]  (bf16 MFMA, split-K x4, fp32)
    gemm_mf<3, true><<<dim3(2, 16, Bx * 4), blk, 0, stream>>>(
        LT, sW, Tx, gp, sP, Tx, nullptr, 0, Dx, Pf32, nullptr,
        Tx, Dx, Tx, 4, nullptr, nullptr);
    reduce4<<<4096, blk, 0, stream>>>(Pf32, attnT);
    // hT[t][c] = sum_d attnT[t][d]*ht_w[c][d] + ht_b[c]   (f16)
    gemm_mf<0, false><<<dim3(4, 16, Bx), blk, 0, stream>>>(
        attnT, sP, Dx, wHt, 0, Dx, hT, sX, Cx, nullptr, nullptr,
        Tx, Cx, Dx, 1, nullptr, ht_b);
    bn_partial<<<Bx * 16, blk, 0, stream>>>(hT, ps, pss);
    bn_final<<<2, blk, 0, stream>>>(ps, pss, mu, rs);
    bn_apply_T<<<dim3(Tx / 64, Cx / 64, Bx), blk, 0, stream>>>(
        inpt, hT, mu, rs, gamma, beta, (float*)d_out);
}

// Round 6
// 236.616 us; speedup vs baseline: 4.4635x; 1.0884x over previous
//
#include <hip/hip_runtime.h>
#include <hip/hip_bf16.h>
#include <math.h>

#define Bx 8
#define Cx 512
#define Dx 256
#define Tx 2048
#define EPSx 1e-5f

typedef _Float16 h16;
typedef __attribute__((ext_vector_type(8))) _Float16 h16x8;
typedef __attribute__((ext_vector_type(8))) short s16x8;
typedef __attribute__((ext_vector_type(4))) float f32x4;

typedef __attribute__((address_space(3))) unsigned int lds_u32;
typedef __attribute__((address_space(1))) const unsigned int glb_u32;

// async 16B global -> LDS DMA. ldsp must be wave-uniform; HW adds lane*16.
__device__ __forceinline__ void cp16(void* ldsp, const void* g) {
    __builtin_amdgcn_global_load_lds((glb_u32*)g, (lds_u32*)ldsp, 16, 0, 0);
}

// ---------------------------------------------------------------------------
// MFMA GEMM core: acc[m][n] = sum_k A[m][k]*B[n][k], 2-byte dtypes (f16/bf16),
// tile 128x128, BK=64, 4 waves (2x2 of 64x64), global_load_lds staging with
// XOR swizzle. Epilogue by MODE:
//   0: f16 out, + optional biasM[row] + biasN[col]                (projection)
//   1: bf16 out = acc * (1/Z[b*N+col])                            (gh' = gh/Z)
//   2: bf16 out = exp(acc); atomicAdd Z[b*N+col] += col sums      (logits)
//   3: f16 out = acc + biasN[col]; atomicAdd Cp[col]+=sum(v),
//      Z[col]+=sum(v^2) over rows (fused BatchNorm stats)         (big GEMM)
// ---------------------------------------------------------------------------
template<int MODE, bool BF>
__global__ __launch_bounds__(256, 4)
void gemm_mf(const h16* __restrict__ A, long aBatch, int lda,
             const h16* __restrict__ B, long bBatch, int ldb,
             void* __restrict__ C, long cBatch, int ldc,
             float* __restrict__ Cp, float* __restrict__ Z,
             int M, int N, int K,
             const float* __restrict__ biasM, const float* __restrict__ biasN) {
    __shared__ h16 As[128 * 64];
    __shared__ h16 Bs[128 * 64];
    const int tid  = threadIdx.x;
    const int lane = tid & 63, wid = tid >> 6;
    const int wm = (wid & 1) * 64, wn = (wid >> 1) * 64;
    const int lm = lane & 15, quad = lane >> 4;
    const int m0 = blockIdx.y * 128, n0 = blockIdx.x * 128;
    const int b = blockIdx.z;
    const h16* Ab = A + (size_t)b * aBatch + (size_t)m0 * lda;
    const h16* Bb = B + (size_t)b * bBatch + (size_t)n0 * ldb;

    const int srow  = tid >> 3;                 // row within 32-row group
    const int sclog = (tid & 7) ^ (srow & 7);   // logical k-chunk (XOR swizzle)
    char* ldsA = (char*)As + (tid & ~63) * 16;  // wave-uniform base
    char* ldsB = (char*)Bs + (tid & ~63) * 16;

    f32x4 acc[4][4] = {};

    for (int k0 = 0; k0 < K; k0 += 64) {
        __syncthreads();   // all waves done reading previous tile
#pragma unroll
        for (int i = 0; i < 4; i++) {
            int r = srow + 32 * i;
            cp16(ldsA + i * 4096, Ab + (size_t)r * lda + k0 + sclog * 8);
        }
#pragma unroll
        for (int i = 0; i < 4; i++) {
            int r = srow + 32 * i;
            cp16(ldsB + i * 4096, Bb + (size_t)r * ldb + k0 + sclog * 8);
        }
        __syncthreads();   // drains vmcnt(0): tile resident
#pragma unroll
        for (int ks = 0; ks < 2; ks++) {
            s16x8 af[4], bf4[4];
#pragma unroll
            for (int i = 0; i < 4; i++) {
                int row = wm + 16 * i + lm;
                int st = (ks * 4 + quad) ^ (lm & 7);
                af[i] = *(const s16x8*)(As + row * 64 + st * 8);
            }
#pragma unroll
            for (int j = 0; j < 4; j++) {
                int row = wn + 16 * j + lm;
                int st = (ks * 4 + quad) ^ (lm & 7);
                bf4[j] = *(const s16x8*)(Bs + row * 64 + st * 8);
            }
#pragma unroll
            for (int i = 0; i < 4; i++)
#pragma unroll
                for (int j = 0; j < 4; j++) {
                    if constexpr (BF)
                        acc[i][j] = __builtin_amdgcn_mfma_f32_16x16x32_bf16(
                            af[i], bf4[j], acc[i][j], 0, 0, 0);
                    else
                        acc[i][j] = __builtin_amdgcn_mfma_f32_16x16x32_f16(
                            __builtin_bit_cast(h16x8, af[i]),
                            __builtin_bit_cast(h16x8, bf4[j]), acc[i][j], 0, 0, 0);
                }
        }
    }

    // epilogue: C/D layout col=lane&15, row=quad*4+reg
    if constexpr (MODE == 0) {
        h16* Cb = (h16*)C + (size_t)b * cBatch;
#pragma unroll
        for (int i = 0; i < 4; i++)
#pragma unroll
            for (int j = 0; j < 4; j++) {
                int row = m0 + wm + 16 * i + quad * 4;
                int col = n0 + wn + 16 * j + lm;
                float bN = biasN ? biasN[col] : 0.0f;
#pragma unroll
                for (int r = 0; r < 4; r++) {
                    float v = acc[i][j][r] + bN;
                    if (biasM) v += biasM[row + r];
                    Cb[(size_t)(row + r) * ldc + col] = (h16)v;
                }
            }
    } else if constexpr (MODE == 1) {
        __hip_bfloat16* Cb = (__hip_bfloat16*)C + (size_t)b * cBatch;
#pragma unroll
        for (int j = 0; j < 4; j++) {
            int col = n0 + wn + 16 * j + lm;
            float iz = 1.0f / Z[(size_t)b * N + col];
#pragma unroll
            for (int i = 0; i < 4; i++) {
                int row = m0 + wm + 16 * i + quad * 4;
#pragma unroll
                for (int r = 0; r < 4; r++)
                    Cb[(size_t)(row + r) * ldc + col] =
                        __float2bfloat16(acc[i][j][r] * iz);
            }
        }
    } else if constexpr (MODE == 2) {
        __syncthreads();                       // fragments consumed
        float* Zl = (float*)As;
        if (tid < 128) Zl[tid] = 0.0f;
        __syncthreads();
        __hip_bfloat16* Cb = (__hip_bfloat16*)C + (size_t)b * cBatch;
#pragma unroll
        for (int j = 0; j < 4; j++) {
            int cl = wn + 16 * j + lm;
            int col = n0 + cl;
            float zp = 0.0f;
#pragma unroll
            for (int i = 0; i < 4; i++) {
                int row = m0 + wm + 16 * i + quad * 4;
#pragma unroll
                for (int r = 0; r < 4; r++) {
                    float e = __expf(acc[i][j][r]);
                    zp += e;
                    Cb[(size_t)(row + r) * ldc + col] = __float2bfloat16(e);
                }
            }
            atomicAdd(&Zl[cl], zp);
        }
        __syncthreads();
        if (tid < 128) atomicAdd(&Z[(size_t)b * N + n0 + tid], Zl[tid]);
    } else {  // MODE 3: f16 out + biasN, fused BN sum/sumsq atomics
        __syncthreads();                       // fragments consumed
        float* Sl = (float*)As;                // [0:128) col sums
        float* Sq = Sl + 128;                  // [128:256) col sumsq
        if (tid < 256) Sl[tid] = 0.0f;
        __syncthreads();
        h16* Cb = (h16*)C + (size_t)b * cBatch;
#pragma unroll
        for (int j = 0; j < 4; j++) {
            int cl = wn + 16 * j + lm;
            int col = n0 + cl;
            float bN = biasN[col];
            float s = 0.0f, q = 0.0f;
#pragma unroll
            for (int i = 0; i < 4; i++) {
                int row = m0 + wm + 16 * i + quad * 4;
#pragma unroll
                for (int r = 0; r < 4; r++) {
                    float v = acc[i][j][r] + bN;
                    s += v;
                    q = fmaf(v, v, q);
                    Cb[(size_t)(row + r) * ldc + col] = (h16)v;
                }
            }
            atomicAdd(&Sl[cl], s);
            atomicAdd(&Sq[cl], q);
        }
        __syncthreads();
        if (tid < 128) {
            atomicAdd(&Cp[n0 + tid], Sl[tid]);
            atomicAdd(&Z[n0 + tid], Sq[tid]);   // FIXED: was Sq[tid+128] (garbage)
        }
    }
}

// ---------------------------------------------------------------------------
// inpt[b][c][t] fp32 -> xT[b][t][c] f16 via 64x64 LDS tile transpose.
// ---------------------------------------------------------------------------
__global__ __launch_bounds__(256)
void conv_x(const float* __restrict__ inpt, h16* __restrict__ xT) {
    __shared__ float lds[64][68];
    const int b = blockIdx.z;
    const int t0 = blockIdx.x * 64, c0 = blockIdx.y * 64;
    const int tid = threadIdx.x, q = tid >> 4, k = tid & 15;
    const float* ib = inpt + (size_t)b * Cx * Tx;
#pragma unroll
    for (int i = 0; i < 4; i++) {
        int c = q + 16 * i;
        float4 v = *(const float4*)(ib + (size_t)(c0 + c) * Tx + t0 + 4 * k);
        *(float4*)&lds[c][4 * k] = v;
    }
    __syncthreads();
    h16* xb = xT + (size_t)b * Tx * Cx;
#pragma unroll
    for (int i = 0; i < 4; i++) {
        int t = q + 16 * i;
        h16 o[4];
#pragma unroll
        for (int j = 0; j < 4; j++) o[j] = (h16)lds[4 * k + j][t];
        *(uint2*)(xb + (size_t)(t0 + t) * Cx + c0 + 4 * k) = *(uint2*)o;
    }
}

// ---------------------------------------------------------------------------
// Weights -> f16 concat (theta|phi|g|ht — already the needed layout).
// block 512: bias3 = theta_b||phi_b||g_b; 513-576: Z=0; 577: psum/pssq=0.
// ---------------------------------------------------------------------------
__global__ __launch_bounds__(256)
void conv_w(const float* __restrict__ w0, const float* __restrict__ w1,
            const float* __restrict__ w2, const float* __restrict__ w3,
            const float* __restrict__ tb, const float* __restrict__ pb,
            const float* __restrict__ gb,
            h16* __restrict__ dst, float* __restrict__ bias3,
            float* __restrict__ Z, float* __restrict__ psum,
            float* __restrict__ pssq) {
    int bx = blockIdx.x;
    int tid = threadIdx.x;
    if (bx == 577) {
        psum[tid] = 0.0f; psum[tid + 256] = 0.0f;
        pssq[tid] = 0.0f; pssq[tid + 256] = 0.0f;
        return;
    }
    if (bx >= 513) { Z[(bx - 513) * 256 + tid] = 0.0f; return; }
    if (bx == 512) {
        bias3[tid] = tb[tid];
        bias3[tid + 256] = pb[tid];
        bias3[tid + 512] = gb[tid];
        return;
    }
    int idx4 = bx * 256 + tid;
    int arr = idx4 >> 15, local4 = idx4 & 32767;
    const float* srcs[4] = {w0, w1, w2, w3};
    float4 v = ((const float4*)srcs[arr])[local4];
    h16 o[4] = {(h16)v.x, (h16)v.y, (h16)v.z, (h16)v.w};
    *(uint2*)(dst + (size_t)arr * 131072 + (size_t)local4 * 4) = *(uint2*)o;
}

// ---------------------------------------------------------------------------
// BN finalize: psum/pssq are complete (atomics from big GEMM).
// ---------------------------------------------------------------------------
__global__ __launch_bounds__(256)
void bn_final(const float* __restrict__ psum, const float* __restrict__ pssq,
              float* __restrict__ mean, float* __restrict__ rsig) {
    int c = blockIdx.x * 256 + threadIdx.x;
    const float invN = 1.0f / (float)(Bx * Tx);
    float mu = psum[c] * invN;
    float var = pssq[c] * invN - mu * mu;
    mean[c] = mu;
    rsig[c] = rsqrtf(var + EPSx);
}

// ---------------------------------------------------------------------------
// out[b][c][t] = inpt + gamma[c]*(hT[b][t][c]-mu)*rsig + beta[c]
// ---------------------------------------------------------------------------
__global__ __launch_bounds__(256)
void bn_apply_T(const float* __restrict__ inpt, const h16* __restrict__ hT,
                const float* __restrict__ mean, const float* __restrict__ rsig,
                const float* __restrict__ gamma, const float* __restrict__ beta,
                float* __restrict__ out) {
    __shared__ float lds[64][68];
    const int b = blockIdx.z, t0 = blockIdx.x * 64, c0 = blockIdx.y * 64;
    const int tid = threadIdx.x, q = tid >> 4, k = tid & 15;
    const h16* hb = hT + (size_t)b * Tx * Cx;
#pragma unroll
    for (int i = 0; i < 4; i++) {
        int t = q + 16 * i;
        uint2 raw = *(const uint2*)(hb + (size_t)(t0 + t) * Cx + c0 + 4 * k);
        const h16* hp = (const h16*)&raw;
        float4 v = make_float4((float)hp[0], (float)hp[1], (float)hp[2], (float)hp[3]);
        *(float4*)&lds[t][4 * k] = v;
    }
    __syncthreads();
    const float* ib = inpt + (size_t)b * Cx * Tx;
    float* ob = out + (size_t)b * Cx * Tx;
#pragma unroll
    for (int i = 0; i < 4; i++) {
        int c = q + 16 * i;
        int cg = c0 + c;
        float mu = mean[cg], rv = rsig[cg], ga = gamma[cg], be = beta[cg];
        float4 x = *(const float4*)(ib + (size_t)cg * Tx + t0 + 4 * k);
        float4 o;
        o.x = x.x + ga * (lds[4 * k + 0][c] - mu) * rv + be;
        o.y = x.y + ga * (lds[4 * k + 1][c] - mu) * rv + be;
        o.z = x.z + ga * (lds[4 * k + 2][c] - mu) * rv + be;
        o.w = x.w + ga * (lds[4 * k + 3][c] - mu) * rv + be;
        *(float4*)(ob + (size_t)cg * Tx + t0 + 4 * k) = o;
    }
}

// ---------------------------------------------------------------------------
// Workspace (bytes, total ~121 MiB):
//   xT    @0            16,777,216  (f16 [b][t][c] -> hT reuse)
//   w4    @16,777,216    1,048,576  (theta|phi|g|ht f16; wTPG=768x512, wHt)
//   bias3 @17,825,792        3,072  (theta_b||phi_b||g_b)
//   Z     @17,828,864       65,536  (fp32 exp-row-sums [b][t])
//   psum  @17,894,400        2,048  (fp32 BN channel sums)
//   pssq  @17,896,448        2,048
//   mean  @17,898,496        2,048
//   rsig  @17,900,544        2,048
//   thpg  @17,902,592   25,165,824  (f16 [b][t][theta||phi||g], ld 768)
//   gh    @43,068,416   16,777,216  (bf16 gh' = (ht_w·g)/Z, [b][c][t])
//   LT    @59,845,632   67,108,864  (bf16 exp-logits [b][s][t])
// ---------------------------------------------------------------------------
extern "C" void kernel_launch(void* const* d_in, const int* in_sizes, int n_in,
                              void* d_out, int out_size, void* d_ws, size_t ws_size,
                              hipStream_t stream) {
    const float* inpt    = (const float*)d_in[0];
    const float* theta_w = (const float*)d_in[1];
    const float* theta_b = (const float*)d_in[2];
    const float* phi_w   = (const float*)d_in[3];
    const float* phi_b   = (const float*)d_in[4];
    const float* g_w     = (const float*)d_in[5];
    const float* g_b     = (const float*)d_in[6];
    const float* ht_w    = (const float*)d_in[7];
    const float* ht_b    = (const float*)d_in[8];
    const float* gamma   = (const float*)d_in[9];
    const float* beta    = (const float*)d_in[10];

    char* ws = (char*)d_ws;
    h16*   xT    = (h16*)(ws + 0);
    h16*   w4    = (h16*)(ws + 16777216);     // wTPG = w4 (768 rows x 512)
    h16*   wHt   = w4 + 393216;               // 512 rows x 256
    float* bias3 = (float*)(ws + 17825792);
    float* Z     = (float*)(ws + 17828864);
    float* psum  = (float*)(ws + 17894400);
    float* pssq  = (float*)(ws + 17896448);
    float* mu    = (float*)(ws + 17898496);
    float* rs    = (float*)(ws + 17900544);
    h16*   thpg  = (h16*)(ws + 17902592);
    h16*   gh    = (h16*)(ws + 43068416);     // bf16 bits
    h16*   LT    = (h16*)(ws + 59845632);     // bf16 bits
    h16*   hT    = xT;                        // reuse: xT dead after proj GEMM

    const long sX  = (long)Tx * Cx;    // 1,048,576 (xT, hT)
    const long sTP = (long)Tx * 768;   // 1,572,864 (thpg)
    const long sGH = (long)Cx * Tx;    // 1,048,576 (gh)
    const long sW  = (long)Tx * Tx;    // 4,194,304 (LT)

    dim3 blk(256);
    conv_x<<<dim3(Tx / 64, Cx / 64, Bx), blk, 0, stream>>>(inpt, xT);
    conv_w<<<578, blk, 0, stream>>>(theta_w, phi_w, g_w, ht_w,
                                    theta_b, phi_b, g_b,
                                    w4, bias3, Z, psum, pssq);
    // thpg[t][n] = sum_c xT[t][c]*(theta||phi||g)[n][c] + bias3[n]   (f16)
    gemm_mf<0, false><<<dim3(6, 16, Bx), blk, 0, stream>>>(
        xT, sX, Cx, w4, 0, Cx, thpg, sTP, 768, nullptr, nullptr,
        Tx, 768, Cx, nullptr, bias3);
    // LT[s][t] = exp(sum_d phi[s][d]*theta[t][d]) bf16; Z[t] += col sums
    gemm_mf<2, false><<<dim3(16, 16, Bx), blk, 0, stream>>>(
        thpg + 256, sTP, 768, thpg, sTP, 768, LT, sW, Tx, nullptr, Z,
        Tx, Tx, Dx, nullptr, nullptr);
    // gh[c][t] = (sum_d ht_w[c][d]*g[t][d]) / Z[t]   (bf16)
    gemm_mf<1, false><<<dim3(16, 4, Bx), blk, 0, stream>>>(
        wHt, 0, Dx, thpg + 512, sTP, 768, gh, sGH, Tx, nullptr, Z,
        Cx, Tx, Dx, nullptr, nullptr);
    // hT[s][c] = sum_t LT[s][t]*gh[c][t] + ht_b[c]; fused BN stat atomics
    gemm_mf<3, true><<<dim3(4, 16, Bx), blk, 0, stream>>>(
        LT, sW, Tx, gh, sGH, Tx, hT, sX, Cx, psum, pssq,
        Tx, Cx, Tx, nullptr, ht_b);
    bn_final<<<2, blk, 0, stream>>>(psum, pssq, mu, rs);
    bn_apply_T<<<dim3(Tx / 64, Cx / 64, Bx), blk, 0, stream>>>(
        inpt, hT, mu, rs, gamma, beta, (float*)d_out);
}

// Round 7
// 229.131 us; speedup vs baseline: 4.6093x; 1.0327x over previous
//
#include <hip/hip_runtime.h>
#include <hip/hip_bf16.h>
#include <math.h>

#define Bx 8
#define Cx 512
#define Dx 256
#define Tx 2048
#define EPSx 1e-5f

typedef _Float16 h16;
typedef __attribute__((ext_vector_type(8))) _Float16 h16x8;
typedef __attribute__((ext_vector_type(8))) short s16x8;
typedef __attribute__((ext_vector_type(4))) float f32x4;

typedef __attribute__((address_space(3))) unsigned int lds_u32;
typedef __attribute__((address_space(1))) const unsigned int glb_u32;

// async 16B global -> LDS DMA. ldsp must be wave-uniform; HW adds lane*16.
__device__ __forceinline__ void cp16(void* ldsp, const void* g) {
    __builtin_amdgcn_global_load_lds((glb_u32*)g, (lds_u32*)ldsp, 16, 0, 0);
}

// ---------------------------------------------------------------------------
// MFMA GEMM core: acc[m][n] = sum_k A[m][k]*B[n][k], 2-byte dtypes (f16/bf16),
// tile 128x128, K-chunk BK (64 or 128), 4 waves (2x2 of 64x64),
// global_load_lds staging with XOR swizzle. Epilogue by MODE:
//   0: f16 out, + optional biasM[row] + biasN[col]                (projection)
//   1: bf16 out = acc * (1/Z[b*N+col])                            (gh' = gh/Z)
//   2: bf16 out = exp(acc); atomicAdd Z[b*N+col] += col sums      (logits)
//   3: f16 out = acc + biasN[col]; atomicAdd Cp[col]+=sum(v),
//      Z[col]+=sum(v^2) (fused BN stats). 1-D grid 512, batch->XCD swizzle.
// ---------------------------------------------------------------------------
template<int MODE, bool BF, int BK>
__global__ __launch_bounds__(256, 4)
void gemm_mf(const h16* __restrict__ A, long aBatch, int lda,
             const h16* __restrict__ B, long bBatch, int ldb,
             void* __restrict__ C, long cBatch, int ldc,
             float* __restrict__ Cp, float* __restrict__ Z,
             int M, int N, int K,
             const float* __restrict__ biasM, const float* __restrict__ biasN) {
    __shared__ h16 As[128 * BK];
    __shared__ h16 Bs[128 * BK];
    const int tid  = threadIdx.x;
    const int lane = tid & 63, wid = tid >> 6;
    const int wm = (wid & 1) * 64, wn = (wid >> 1) * 64;
    const int lm = lane & 15, quad = lane >> 4;
    int m0, n0, b;
    if constexpr (MODE == 3) {
        // batch->XCD swizzle: all 64 blocks of batch b land on XCD b (id%8).
        int id = blockIdx.x;
        b = id & 7;
        int rr = id >> 3;
        m0 = (rr & 15) << 7;
        n0 = (rr >> 4) << 7;
    } else {
        m0 = blockIdx.y * 128; n0 = blockIdx.x * 128; b = blockIdx.z;
    }
    const h16* Ab = A + (size_t)b * aBatch + (size_t)m0 * lda;
    const h16* Bb = B + (size_t)b * bBatch + (size_t)n0 * ldb;

    // staging map: CH 16B-chunks per row; round covers 2048/BK rows.
    constexpr int CH  = BK / 8;        // chunks per row
    constexpr int RPR = 2048 / BK;     // rows per 4KB round
    constexpr int RND = BK / 16;       // rounds per 128-row tile
    const int srow  = tid / CH;                       // row within round
    const int sclog = (tid & (CH - 1)) ^ (srow & 7);  // logical k-chunk (XOR)
    char* ldsA = (char*)As + (tid & ~63) * 16;        // wave-uniform base
    char* ldsB = (char*)Bs + (tid & ~63) * 16;

    f32x4 acc[4][4] = {};

    for (int k0 = 0; k0 < K; k0 += BK) {
        __syncthreads();   // all waves done reading previous tile
#pragma unroll
        for (int i = 0; i < RND; i++) {
            int r = srow + RPR * i;
            cp16(ldsA + i * 4096, Ab + (size_t)r * lda + k0 + sclog * 8);
        }
#pragma unroll
        for (int i = 0; i < RND; i++) {
            int r = srow + RPR * i;
            cp16(ldsB + i * 4096, Bb + (size_t)r * ldb + k0 + sclog * 8);
        }
        __syncthreads();   // drains vmcnt(0): tile resident
#pragma unroll
        for (int ks = 0; ks < BK / 32; ks++) {
            s16x8 af[4], bf4[4];
#pragma unroll
            for (int i = 0; i < 4; i++) {
                int row = wm + 16 * i + lm;
                int st = (ks * 4 + quad) ^ (lm & 7);
                af[i] = *(const s16x8*)(As + row * BK + st * 8);
            }
#pragma unroll
            for (int j = 0; j < 4; j++) {
                int row = wn + 16 * j + lm;
                int st = (ks * 4 + quad) ^ (lm & 7);
                bf4[j] = *(const s16x8*)(Bs + row * BK + st * 8);
            }
#pragma unroll
            for (int i = 0; i < 4; i++)
#pragma unroll
                for (int j = 0; j < 4; j++) {
                    if constexpr (BF)
                        acc[i][j] = __builtin_amdgcn_mfma_f32_16x16x32_bf16(
                            af[i], bf4[j], acc[i][j], 0, 0, 0);
                    else
                        acc[i][j] = __builtin_amdgcn_mfma_f32_16x16x32_f16(
                            __builtin_bit_cast(h16x8, af[i]),
                            __builtin_bit_cast(h16x8, bf4[j]), acc[i][j], 0, 0, 0);
                }
        }
    }

    // epilogue: C/D layout col=lane&15, row=quad*4+reg
    if constexpr (MODE == 0) {
        h16* Cb = (h16*)C + (size_t)b * cBatch;
#pragma unroll
        for (int i = 0; i < 4; i++)
#pragma unroll
            for (int j = 0; j < 4; j++) {
                int row = m0 + wm + 16 * i + quad * 4;
                int col = n0 + wn + 16 * j + lm;
                float bN = biasN ? biasN[col] : 0.0f;
#pragma unroll
                for (int r = 0; r < 4; r++) {
                    float v = acc[i][j][r] + bN;
                    if (biasM) v += biasM[row + r];
                    Cb[(size_t)(row + r) * ldc + col] = (h16)v;
                }
            }
    } else if constexpr (MODE == 1) {
        __hip_bfloat16* Cb = (__hip_bfloat16*)C + (size_t)b * cBatch;
#pragma unroll
        for (int j = 0; j < 4; j++) {
            int col = n0 + wn + 16 * j + lm;
            float iz = 1.0f / Z[(size_t)b * N + col];
#pragma unroll
            for (int i = 0; i < 4; i++) {
                int row = m0 + wm + 16 * i + quad * 4;
#pragma unroll
                for (int r = 0; r < 4; r++)
                    Cb[(size_t)(row + r) * ldc + col] =
                        __float2bfloat16(acc[i][j][r] * iz);
            }
        }
    } else if constexpr (MODE == 2) {
        __syncthreads();                       // fragments consumed
        float* Zl = (float*)As;
        if (tid < 128) Zl[tid] = 0.0f;
        __syncthreads();
        __hip_bfloat16* Cb = (__hip_bfloat16*)C + (size_t)b * cBatch;
#pragma unroll
        for (int j = 0; j < 4; j++) {
            int cl = wn + 16 * j + lm;
            int col = n0 + cl;
            float zp = 0.0f;
#pragma unroll
            for (int i = 0; i < 4; i++) {
                int row = m0 + wm + 16 * i + quad * 4;
#pragma unroll
                for (int r = 0; r < 4; r++) {
                    float e = __expf(acc[i][j][r]);
                    zp += e;
                    Cb[(size_t)(row + r) * ldc + col] = __float2bfloat16(e);
                }
            }
            atomicAdd(&Zl[cl], zp);
        }
        __syncthreads();
        if (tid < 128) atomicAdd(&Z[(size_t)b * N + n0 + tid], Zl[tid]);
    } else {  // MODE 3: f16 out + biasN, fused BN sum/sumsq atomics
        __syncthreads();                       // fragments consumed
        float* Sl = (float*)As;                // [0:128) col sums
        float* Sq = Sl + 128;                  // [128:256) col sumsq
        if (tid < 256) Sl[tid] = 0.0f;
        __syncthreads();
        h16* Cb = (h16*)C + (size_t)b * cBatch;
#pragma unroll
        for (int j = 0; j < 4; j++) {
            int cl = wn + 16 * j + lm;
            int col = n0 + cl;
            float bN = biasN[col];
            float s = 0.0f, q = 0.0f;
#pragma unroll
            for (int i = 0; i < 4; i++) {
                int row = m0 + wm + 16 * i + quad * 4;
#pragma unroll
                for (int r = 0; r < 4; r++) {
                    float v = acc[i][j][r] + bN;
                    s += v;
                    q = fmaf(v, v, q);
                    Cb[(size_t)(row + r) * ldc + col] = (h16)v;
                }
            }
            atomicAdd(&Sl[cl], s);
            atomicAdd(&Sq[cl], q);
        }
        __syncthreads();
        if (tid < 128) {
            atomicAdd(&Cp[n0 + tid], Sl[tid]);
            atomicAdd(&Z[n0 + tid], Sq[tid]);
        }
    }
}

// ---------------------------------------------------------------------------
// inpt[b][c][t] fp32 -> xT[b][t][c] f16 via 64x64 LDS tile transpose.
// ---------------------------------------------------------------------------
__global__ __launch_bounds__(256)
void conv_x(const float* __restrict__ inpt, h16* __restrict__ xT) {
    __shared__ float lds[64][68];
    const int b = blockIdx.z;
    const int t0 = blockIdx.x * 64, c0 = blockIdx.y * 64;
    const int tid = threadIdx.x, q = tid >> 4, k = tid & 15;
    const float* ib = inpt + (size_t)b * Cx * Tx;
#pragma unroll
    for (int i = 0; i < 4; i++) {
        int c = q + 16 * i;
        float4 v = *(const float4*)(ib + (size_t)(c0 + c) * Tx + t0 + 4 * k);
        *(float4*)&lds[c][4 * k] = v;
    }
    __syncthreads();
    h16* xb = xT + (size_t)b * Tx * Cx;
#pragma unroll
    for (int i = 0; i < 4; i++) {
        int t = q + 16 * i;
        h16 o[4];
#pragma unroll
        for (int j = 0; j < 4; j++) o[j] = (h16)lds[4 * k + j][t];
        *(uint2*)(xb + (size_t)(t0 + t) * Cx + c0 + 4 * k) = *(uint2*)o;
    }
}

// ---------------------------------------------------------------------------
// Weights -> f16 concat (theta|phi|g|ht — already the needed layout).
// block 512: bias3 = theta_b||phi_b||g_b; 513-576: Z=0; 577: psum/pssq=0.
// ---------------------------------------------------------------------------
__global__ __launch_bounds__(256)
void conv_w(const float* __restrict__ w0, const float* __restrict__ w1,
            const float* __restrict__ w2, const float* __restrict__ w3,
            const float* __restrict__ tb, const float* __restrict__ pb,
            const float* __restrict__ gb,
            h16* __restrict__ dst, float* __restrict__ bias3,
            float* __restrict__ Z, float* __restrict__ psum,
            float* __restrict__ pssq) {
    int bx = blockIdx.x;
    int tid = threadIdx.x;
    if (bx == 577) {
        psum[tid] = 0.0f; psum[tid + 256] = 0.0f;
        pssq[tid] = 0.0f; pssq[tid + 256] = 0.0f;
        return;
    }
    if (bx >= 513) { Z[(bx - 513) * 256 + tid] = 0.0f; return; }
    if (bx == 512) {
        bias3[tid] = tb[tid];
        bias3[tid + 256] = pb[tid];
        bias3[tid + 512] = gb[tid];
        return;
    }
    int idx4 = bx * 256 + tid;
    int arr = idx4 >> 15, local4 = idx4 & 32767;
    const float* srcs[4] = {w0, w1, w2, w3};
    float4 v = ((const float4*)srcs[arr])[local4];
    h16 o[4] = {(h16)v.x, (h16)v.y, (h16)v.z, (h16)v.w};
    *(uint2*)(dst + (size_t)arr * 131072 + (size_t)local4 * 4) = *(uint2*)o;
}

// ---------------------------------------------------------------------------
// out[b][c][t] = inpt + gamma[c]*(hT[b][t][c]-mu)*rsig + beta[c]
// BN finalize fused: mu/rsig computed inline from psum/pssq.
// ---------------------------------------------------------------------------
__global__ __launch_bounds__(256)
void bn_apply_T(const float* __restrict__ inpt, const h16* __restrict__ hT,
                const float* __restrict__ psum, const float* __restrict__ pssq,
                const float* __restrict__ gamma, const float* __restrict__ beta,
                float* __restrict__ out) {
    __shared__ float lds[64][68];
    const int b = blockIdx.z, t0 = blockIdx.x * 64, c0 = blockIdx.y * 64;
    const int tid = threadIdx.x, q = tid >> 4, k = tid & 15;
    const h16* hb = hT + (size_t)b * Tx * Cx;
#pragma unroll
    for (int i = 0; i < 4; i++) {
        int t = q + 16 * i;
        uint2 raw = *(const uint2*)(hb + (size_t)(t0 + t) * Cx + c0 + 4 * k);
        const h16* hp = (const h16*)&raw;
        float4 v = make_float4((float)hp[0], (float)hp[1], (float)hp[2], (float)hp[3]);
        *(float4*)&lds[t][4 * k] = v;
    }
    __syncthreads();
    const float* ib = inpt + (size_t)b * Cx * Tx;
    float* ob = out + (size_t)b * Cx * Tx;
    const float invN = 1.0f / (float)(Bx * Tx);
#pragma unroll
    for (int i = 0; i < 4; i++) {
        int c = q + 16 * i;
        int cg = c0 + c;
        float mu = psum[cg] * invN;
        float var = pssq[cg] * invN - mu * mu;
        float rv = rsqrtf(var + EPSx);
        float ga = gamma[cg], be = beta[cg];
        float4 x = *(const float4*)(ib + (size_t)cg * Tx + t0 + 4 * k);
        float4 o;
        o.x = x.x + ga * (lds[4 * k + 0][c] - mu) * rv + be;
        o.y = x.y + ga * (lds[4 * k + 1][c] - mu) * rv + be;
        o.z = x.z + ga * (lds[4 * k + 2][c] - mu) * rv + be;
        o.w = x.w + ga * (lds[4 * k + 3][c] - mu) * rv + be;
        *(float4*)(ob + (size_t)cg * Tx + t0 + 4 * k) = o;
    }
}

// ---------------------------------------------------------------------------
// Workspace (bytes, total ~121 MiB):
//   xT    @0            16,777,216  (f16 [b][t][c] -> hT reuse)
//   w4    @16,777,216    1,048,576  (theta|phi|g|ht f16; wTPG=768x512, wHt)
//   bias3 @17,825,792        3,072  (theta_b||phi_b||g_b)
//   Z     @17,828,864       65,536  (fp32 exp-row-sums [b][t])
//   psum  @17,894,400        2,048  (fp32 BN channel sums)
//   pssq  @17,896,448        2,048
//   thpg  @17,902,592   25,165,824  (f16 [b][t][theta||phi||g], ld 768)
//   gh    @43,068,416   16,777,216  (bf16 gh' = (ht_w·g)/Z, [b][c][t])
//   LT    @59,845,632   67,108,864  (bf16 exp-logits [b][s][t])
// ---------------------------------------------------------------------------
extern "C" void kernel_launch(void* const* d_in, const int* in_sizes, int n_in,
                              void* d_out, int out_size, void* d_ws, size_t ws_size,
                              hipStream_t stream) {
    const float* inpt    = (const float*)d_in[0];
    const float* theta_w = (const float*)d_in[1];
    const float* theta_b = (const float*)d_in[2];
    const float* phi_w   = (const float*)d_in[3];
    const float* phi_b   = (const float*)d_in[4];
    const float* g_w     = (const float*)d_in[5];
    const float* g_b     = (const float*)d_in[6];
    const float* ht_w    = (const float*)d_in[7];
    const float* ht_b    = (const float*)d_in[8];
    const float* gamma   = (const float*)d_in[9];
    const float* beta    = (const float*)d_in[10];

    char* ws = (char*)d_ws;
    h16*   xT    = (h16*)(ws + 0);
    h16*   w4    = (h16*)(ws + 16777216);     // wTPG = w4 (768 rows x 512)
    h16*   wHt   = w4 + 393216;               // 512 rows x 256
    float* bias3 = (float*)(ws + 17825792);
    float* Z     = (float*)(ws + 17828864);
    float* psum  = (float*)(ws + 17894400);
    float* pssq  = (float*)(ws + 17896448);
    h16*   thpg  = (h16*)(ws + 17902592);
    h16*   gh    = (h16*)(ws + 43068416);     // bf16 bits
    h16*   LT    = (h16*)(ws + 59845632);     // bf16 bits
    h16*   hT    = xT;                        // reuse: xT dead after proj GEMM

    const long sX  = (long)Tx * Cx;    // 1,048,576 (xT, hT)
    const long sTP = (long)Tx * 768;   // 1,572,864 (thpg)
    const long sGH = (long)Cx * Tx;    // 1,048,576 (gh)
    const long sW  = (long)Tx * Tx;    // 4,194,304 (LT)

    dim3 blk(256);
    conv_x<<<dim3(Tx / 64, Cx / 64, Bx), blk, 0, stream>>>(inpt, xT);
    conv_w<<<578, blk, 0, stream>>>(theta_w, phi_w, g_w, ht_w,
                                    theta_b, phi_b, g_b,
                                    w4, bias3, Z, psum, pssq);
    // thpg[t][n] = sum_c xT[t][c]*(theta||phi||g)[n][c] + bias3[n]   (f16)
    gemm_mf<0, false, 64><<<dim3(6, 16, Bx), blk, 0, stream>>>(
        xT, sX, Cx, w4, 0, Cx, thpg, sTP, 768, nullptr, nullptr,
        Tx, 768, Cx, nullptr, bias3);
    // LT[s][t] = exp(sum_d phi[s][d]*theta[t][d]) bf16; Z[t] += col sums
    gemm_mf<2, false, 64><<<dim3(16, 16, Bx), blk, 0, stream>>>(
        thpg + 256, sTP, 768, thpg, sTP, 768, LT, sW, Tx, nullptr, Z,
        Tx, Tx, Dx, nullptr, nullptr);
    // gh[c][t] = (sum_d ht_w[c][d]*g[t][d]) / Z[t]   (bf16)
    gemm_mf<1, false, 64><<<dim3(16, 4, Bx), blk, 0, stream>>>(
        wHt, 0, Dx, thpg + 512, sTP, 768, gh, sGH, Tx, nullptr, Z,
        Cx, Tx, Dx, nullptr, nullptr);
    // hT[s][c] = sum_t LT[s][t]*gh[c][t] + ht_b[c]; fused BN stat atomics
    // BK=128, 1-D grid with batch->XCD swizzle.
    gemm_mf<3, true, 128><<<dim3(512), blk, 0, stream>>>(
        LT, sW, Tx, gh, sGH, Tx, hT, sX, Cx, psum, pssq,
        Tx, Cx, Tx, nullptr, ht_b);
    bn_apply_T<<<dim3(Tx / 64, Cx / 64, Bx), blk, 0, stream>>>(
        inpt, hT, psum, pssq, gamma, beta, (float*)d_out);
}

// Round 8
// 225.707 us; speedup vs baseline: 4.6793x; 1.0152x over previous
//
#include <hip/hip_runtime.h>
#include <hip/hip_bf16.h>
#include <math.h>

#define Bx 8
#define Cx 512
#define Dx 256
#define Tx 2048
#define EPSx 1e-5f

typedef _Float16 h16;
typedef __attribute__((ext_vector_type(8))) _Float16 h16x8;
typedef __attribute__((ext_vector_type(8))) short s16x8;
typedef __attribute__((ext_vector_type(4))) float f32x4;

typedef __attribute__((address_space(3))) unsigned int lds_u32;
typedef __attribute__((address_space(1))) const unsigned int glb_u32;

// async 16B global -> LDS DMA. ldsp must be wave-uniform; HW adds lane*16.
__device__ __forceinline__ void cp16(void* ldsp, const void* g) {
    __builtin_amdgcn_global_load_lds((glb_u32*)g, (lds_u32*)ldsp, 16, 0, 0);
}

// ---------------------------------------------------------------------------
// MFMA GEMM core: acc[m][n] = sum_k A[m][k]*B[n][k], 2-byte dtypes (f16/bf16),
// tile 128x128, BK=64 (proven 0-conflict LDS layout), 4 waves (2x2 of 64x64),
// global_load_lds staging with XOR swizzle.
// Grid: 1-D, batch->XCD swizzle: b = id & 7 (all blocks of batch b on one
// XCD -> per-batch operand slices stay L2-hot; r7 measured FETCH 147->41MB).
// rr = id >> 3; m0 = (rr % mBlk)*128; n0 = (rr / mBlk)*128.
// Epilogue by MODE:
//   0: f16 out, + optional biasM[row] + biasN[col]                (projection)
//   1: bf16 out = acc * (1/Z[b*N+col])                            (gh' = gh/Z)
//   2: bf16 out = exp(acc); atomicAdd Z[b*N+col] += col sums      (logits)
//   3: f16 out = acc + biasN[col]; atomicAdd Cp[col]+=sum(v),
//      Z[col]+=sum(v^2) (fused BatchNorm stats)                   (big GEMM)
// ---------------------------------------------------------------------------
template<int MODE, bool BF>
__global__ __launch_bounds__(256, 4)
void gemm_mf(const h16* __restrict__ A, long aBatch, int lda,
             const h16* __restrict__ B, long bBatch, int ldb,
             void* __restrict__ C, long cBatch, int ldc,
             float* __restrict__ Cp, float* __restrict__ Z,
             int M, int N, int K, int mBlk,
             const float* __restrict__ biasM, const float* __restrict__ biasN) {
    __shared__ h16 As[128 * 64];
    __shared__ h16 Bs[128 * 64];
    const int tid  = threadIdx.x;
    const int lane = tid & 63, wid = tid >> 6;
    const int wm = (wid & 1) * 64, wn = (wid >> 1) * 64;
    const int lm = lane & 15, quad = lane >> 4;
    const unsigned id = blockIdx.x;
    const int b = id & 7;
    const unsigned rr = id >> 3;
    const int m0 = (rr % (unsigned)mBlk) * 128;
    const int n0 = (rr / (unsigned)mBlk) * 128;
    const h16* Ab = A + (size_t)b * aBatch + (size_t)m0 * lda;
    const h16* Bb = B + (size_t)b * bBatch + (size_t)n0 * ldb;

    const int srow  = tid >> 3;                 // row within 32-row group
    const int sclog = (tid & 7) ^ (srow & 7);   // logical k-chunk (XOR swizzle)
    char* ldsA = (char*)As + (tid & ~63) * 16;  // wave-uniform base
    char* ldsB = (char*)Bs + (tid & ~63) * 16;

    f32x4 acc[4][4] = {};

    for (int k0 = 0; k0 < K; k0 += 64) {
        __syncthreads();   // all waves done reading previous tile
#pragma unroll
        for (int i = 0; i < 4; i++) {
            int r = srow + 32 * i;
            cp16(ldsA + i * 4096, Ab + (size_t)r * lda + k0 + sclog * 8);
        }
#pragma unroll
        for (int i = 0; i < 4; i++) {
            int r = srow + 32 * i;
            cp16(ldsB + i * 4096, Bb + (size_t)r * ldb + k0 + sclog * 8);
        }
        __syncthreads();   // drains vmcnt(0): tile resident
#pragma unroll
        for (int ks = 0; ks < 2; ks++) {
            s16x8 af[4], bf4[4];
#pragma unroll
            for (int i = 0; i < 4; i++) {
                int row = wm + 16 * i + lm;
                int st = (ks * 4 + quad) ^ (lm & 7);
                af[i] = *(const s16x8*)(As + row * 64 + st * 8);
            }
#pragma unroll
            for (int j = 0; j < 4; j++) {
                int row = wn + 16 * j + lm;
                int st = (ks * 4 + quad) ^ (lm & 7);
                bf4[j] = *(const s16x8*)(Bs + row * 64 + st * 8);
            }
#pragma unroll
            for (int i = 0; i < 4; i++)
#pragma unroll
                for (int j = 0; j < 4; j++) {
                    if constexpr (BF)
                        acc[i][j] = __builtin_amdgcn_mfma_f32_16x16x32_bf16(
                            af[i], bf4[j], acc[i][j], 0, 0, 0);
                    else
                        acc[i][j] = __builtin_amdgcn_mfma_f32_16x16x32_f16(
                            __builtin_bit_cast(h16x8, af[i]),
                            __builtin_bit_cast(h16x8, bf4[j]), acc[i][j], 0, 0, 0);
                }
        }
    }

    // epilogue: C/D layout col=lane&15, row=quad*4+reg
    if constexpr (MODE == 0) {
        h16* Cb = (h16*)C + (size_t)b * cBatch;
#pragma unroll
        for (int i = 0; i < 4; i++)
#pragma unroll
            for (int j = 0; j < 4; j++) {
                int row = m0 + wm + 16 * i + quad * 4;
                int col = n0 + wn + 16 * j + lm;
                float bN = biasN ? biasN[col] : 0.0f;
#pragma unroll
                for (int r = 0; r < 4; r++) {
                    float v = acc[i][j][r] + bN;
                    if (biasM) v += biasM[row + r];
                    Cb[(size_t)(row + r) * ldc + col] = (h16)v;
                }
            }
    } else if constexpr (MODE == 1) {
        __hip_bfloat16* Cb = (__hip_bfloat16*)C + (size_t)b * cBatch;
#pragma unroll
        for (int j = 0; j < 4; j++) {
            int col = n0 + wn + 16 * j + lm;
            float iz = 1.0f / Z[(size_t)b * N + col];
#pragma unroll
            for (int i = 0; i < 4; i++) {
                int row = m0 + wm + 16 * i + quad * 4;
#pragma unroll
                for (int r = 0; r < 4; r++)
                    Cb[(size_t)(row + r) * ldc + col] =
                        __float2bfloat16(acc[i][j][r] * iz);
            }
        }
    } else if constexpr (MODE == 2) {
        __syncthreads();                       // fragments consumed
        float* Zl = (float*)As;
        if (tid < 128) Zl[tid] = 0.0f;
        __syncthreads();
        __hip_bfloat16* Cb = (__hip_bfloat16*)C + (size_t)b * cBatch;
#pragma unroll
        for (int j = 0; j < 4; j++) {
            int cl = wn + 16 * j + lm;
            int col = n0 + cl;
            float zp = 0.0f;
#pragma unroll
            for (int i = 0; i < 4; i++) {
                int row = m0 + wm + 16 * i + quad * 4;
#pragma unroll
                for (int r = 0; r < 4; r++) {
                    float e = __expf(acc[i][j][r]);
                    zp += e;
                    Cb[(size_t)(row + r) * ldc + col] = __float2bfloat16(e);
                }
            }
            atomicAdd(&Zl[cl], zp);
        }
        __syncthreads();
        if (tid < 128) atomicAdd(&Z[(size_t)b * N + n0 + tid], Zl[tid]);
    } else {  // MODE 3: f16 out + biasN, fused BN sum/sumsq atomics
        __syncthreads();                       // fragments consumed
        float* Sl = (float*)As;                // [0:128) col sums
        float* Sq = Sl + 128;                  // [128:256) col sumsq
        if (tid < 256) Sl[tid] = 0.0f;
        __syncthreads();
        h16* Cb = (h16*)C + (size_t)b * cBatch;
#pragma unroll
        for (int j = 0; j < 4; j++) {
            int cl = wn + 16 * j + lm;
            int col = n0 + cl;
            float bN = biasN[col];
            float s = 0.0f, q = 0.0f;
#pragma unroll
            for (int i = 0; i < 4; i++) {
                int row = m0 + wm + 16 * i + quad * 4;
#pragma unroll
                for (int r = 0; r < 4; r++) {
                    float v = acc[i][j][r] + bN;
                    s += v;
                    q = fmaf(v, v, q);
                    Cb[(size_t)(row + r) * ldc + col] = (h16)v;
                }
            }
            atomicAdd(&Sl[cl], s);
            atomicAdd(&Sq[cl], q);
        }
        __syncthreads();
        if (tid < 128) {
            atomicAdd(&Cp[n0 + tid], Sl[tid]);
            atomicAdd(&Z[n0 + tid], Sq[tid]);
        }
    }
}

// ---------------------------------------------------------------------------
// inpt[b][c][t] fp32 -> xT[b][t][c] f16 via 64x64 LDS tile transpose.
// ---------------------------------------------------------------------------
__global__ __launch_bounds__(256)
void conv_x(const float* __restrict__ inpt, h16* __restrict__ xT) {
    __shared__ float lds[64][68];
    const int b = blockIdx.z;
    const int t0 = blockIdx.x * 64, c0 = blockIdx.y * 64;
    const int tid = threadIdx.x, q = tid >> 4, k = tid & 15;
    const float* ib = inpt + (size_t)b * Cx * Tx;
#pragma unroll
    for (int i = 0; i < 4; i++) {
        int c = q + 16 * i;
        float4 v = *(const float4*)(ib + (size_t)(c0 + c) * Tx + t0 + 4 * k);
        *(float4*)&lds[c][4 * k] = v;
    }
    __syncthreads();
    h16* xb = xT + (size_t)b * Tx * Cx;
#pragma unroll
    for (int i = 0; i < 4; i++) {
        int t = q + 16 * i;
        h16 o[4];
#pragma unroll
        for (int j = 0; j < 4; j++) o[j] = (h16)lds[4 * k + j][t];
        *(uint2*)(xb + (size_t)(t0 + t) * Cx + c0 + 4 * k) = *(uint2*)o;
    }
}

// ---------------------------------------------------------------------------
// Weights -> f16 concat (theta|phi|g|ht — already the needed layout).
// block 512: bias3 = theta_b||phi_b||g_b; 513-576: Z=0; 577: psum/pssq=0.
// ---------------------------------------------------------------------------
__global__ __launch_bounds__(256)
void conv_w(const float* __restrict__ w0, const float* __restrict__ w1,
            const float* __restrict__ w2, const float* __restrict__ w3,
            const float* __restrict__ tb, const float* __restrict__ pb,
            const float* __restrict__ gb,
            h16* __restrict__ dst, float* __restrict__ bias3,
            float* __restrict__ Z, float* __restrict__ psum,
            float* __restrict__ pssq) {
    int bx = blockIdx.x;
    int tid = threadIdx.x;
    if (bx == 577) {
        psum[tid] = 0.0f; psum[tid + 256] = 0.0f;
        pssq[tid] = 0.0f; pssq[tid + 256] = 0.0f;
        return;
    }
    if (bx >= 513) { Z[(bx - 513) * 256 + tid] = 0.0f; return; }
    if (bx == 512) {
        bias3[tid] = tb[tid];
        bias3[tid + 256] = pb[tid];
        bias3[tid + 512] = gb[tid];
        return;
    }
    int idx4 = bx * 256 + tid;
    int arr = idx4 >> 15, local4 = idx4 & 32767;
    const float* srcs[4] = {w0, w1, w2, w3};
    float4 v = ((const float4*)srcs[arr])[local4];
    h16 o[4] = {(h16)v.x, (h16)v.y, (h16)v.z, (h16)v.w};
    *(uint2*)(dst + (size_t)arr * 131072 + (size_t)local4 * 4) = *(uint2*)o;
}

// ---------------------------------------------------------------------------
// out[b][c][t] = inpt + gamma[c]*(hT[b][t][c]-mu)*rsig + beta[c]
// BN finalize fused: mu/rsig computed inline from psum/pssq.
// ---------------------------------------------------------------------------
__global__ __launch_bounds__(256)
void bn_apply_T(const float* __restrict__ inpt, const h16* __restrict__ hT,
                const float* __restrict__ psum, const float* __restrict__ pssq,
                const float* __restrict__ gamma, const float* __restrict__ beta,
                float* __restrict__ out) {
    __shared__ float lds[64][68];
    const int b = blockIdx.z, t0 = blockIdx.x * 64, c0 = blockIdx.y * 64;
    const int tid = threadIdx.x, q = tid >> 4, k = tid & 15;
    const h16* hb = hT + (size_t)b * Tx * Cx;
#pragma unroll
    for (int i = 0; i < 4; i++) {
        int t = q + 16 * i;
        uint2 raw = *(const uint2*)(hb + (size_t)(t0 + t) * Cx + c0 + 4 * k);
        const h16* hp = (const h16*)&raw;
        float4 v = make_float4((float)hp[0], (float)hp[1], (float)hp[2], (float)hp[3]);
        *(float4*)&lds[t][4 * k] = v;
    }
    __syncthreads();
    const float* ib = inpt + (size_t)b * Cx * Tx;
    float* ob = out + (size_t)b * Cx * Tx;
    const float invN = 1.0f / (float)(Bx * Tx);
#pragma unroll
    for (int i = 0; i < 4; i++) {
        int c = q + 16 * i;
        int cg = c0 + c;
        float mu = psum[cg] * invN;
        float var = pssq[cg] * invN - mu * mu;
        float rv = rsqrtf(var + EPSx);
        float ga = gamma[cg], be = beta[cg];
        float4 x = *(const float4*)(ib + (size_t)cg * Tx + t0 + 4 * k);
        float4 o;
        o.x = x.x + ga * (lds[4 * k + 0][c] - mu) * rv + be;
        o.y = x.y + ga * (lds[4 * k + 1][c] - mu) * rv + be;
        o.z = x.z + ga * (lds[4 * k + 2][c] - mu) * rv + be;
        o.w = x.w + ga * (lds[4 * k + 3][c] - mu) * rv + be;
        *(float4*)(ob + (size_t)cg * Tx + t0 + 4 * k) = o;
    }
}

// ---------------------------------------------------------------------------
// Workspace (bytes, total ~121 MiB):
//   xT    @0            16,777,216  (f16 [b][t][c] -> hT reuse)
//   w4    @16,777,216    1,048,576  (theta|phi|g|ht f16; wTPG=768x512, wHt)
//   bias3 @17,825,792        3,072  (theta_b||phi_b||g_b)
//   Z     @17,828,864       65,536  (fp32 exp-row-sums [b][t])
//   psum  @17,894,400        2,048  (fp32 BN channel sums)
//   pssq  @17,896,448        2,048
//   thpg  @17,902,592   25,165,824  (f16 [b][t][theta||phi||g], ld 768)
//   gh    @43,068,416   16,777,216  (bf16 gh' = (ht_w·g)/Z, [b][c][t])
//   LT    @59,845,632   67,108,864  (bf16 exp-logits [b][s][t])
// ---------------------------------------------------------------------------
extern "C" void kernel_launch(void* const* d_in, const int* in_sizes, int n_in,
                              void* d_out, int out_size, void* d_ws, size_t ws_size,
                              hipStream_t stream) {
    const float* inpt    = (const float*)d_in[0];
    const float* theta_w = (const float*)d_in[1];
    const float* theta_b = (const float*)d_in[2];
    const float* phi_w   = (const float*)d_in[3];
    const float* phi_b   = (const float*)d_in[4];
    const float* g_w     = (const float*)d_in[5];
    const float* g_b     = (const float*)d_in[6];
    const float* ht_w    = (const float*)d_in[7];
    const float* ht_b    = (const float*)d_in[8];
    const float* gamma   = (const float*)d_in[9];
    const float* beta    = (const float*)d_in[10];

    char* ws = (char*)d_ws;
    h16*   xT    = (h16*)(ws + 0);
    h16*   w4    = (h16*)(ws + 16777216);     // wTPG = w4 (768 rows x 512)
    h16*   wHt   = w4 + 393216;               // 512 rows x 256
    float* bias3 = (float*)(ws + 17825792);
    float* Z     = (float*)(ws + 17828864);
    float* psum  = (float*)(ws + 17894400);
    float* pssq  = (float*)(ws + 17896448);
    h16*   thpg  = (h16*)(ws + 17902592);
    h16*   gh    = (h16*)(ws + 43068416);     // bf16 bits
    h16*   LT    = (h16*)(ws + 59845632);     // bf16 bits
    h16*   hT    = xT;                        // reuse: xT dead after proj GEMM

    const long sX  = (long)Tx * Cx;    // 1,048,576 (xT, hT)
    const long sTP = (long)Tx * 768;   // 1,572,864 (thpg)
    const long sGH = (long)Cx * Tx;    // 1,048,576 (gh)
    const long sW  = (long)Tx * Tx;    // 4,194,304 (LT)

    dim3 blk(256);
    conv_x<<<dim3(Tx / 64, Cx / 64, Bx), blk, 0, stream>>>(inpt, xT);
    conv_w<<<578, blk, 0, stream>>>(theta_w, phi_w, g_w, ht_w,
                                    theta_b, phi_b, g_b,
                                    w4, bias3, Z, psum, pssq);
    // thpg[t][n] = sum_c xT[t][c]*(theta||phi||g)[n][c] + bias3[n]   (f16)
    // grid: 8 batches x (16 m-blk x 6 n-blk) = 768
    gemm_mf<0, false><<<dim3(768), blk, 0, stream>>>(
        xT, sX, Cx, w4, 0, Cx, thpg, sTP, 768, nullptr, nullptr,
        Tx, 768, Cx, 16, nullptr, bias3);
    // LT[s][t] = exp(sum_d phi[s][d]*theta[t][d]) bf16; Z[t] += col sums
    // grid: 8 x (16 x 16) = 2048
    gemm_mf<2, false><<<dim3(2048), blk, 0, stream>>>(
        thpg + 256, sTP, 768, thpg, sTP, 768, LT, sW, Tx, nullptr, Z,
        Tx, Tx, Dx, 16, nullptr, nullptr);
    // gh[c][t] = (sum_d ht_w[c][d]*g[t][d]) / Z[t]   (bf16)
    // grid: 8 x (4 x 16) = 512
    gemm_mf<1, false><<<dim3(512), blk, 0, stream>>>(
        wHt, 0, Dx, thpg + 512, sTP, 768, gh, sGH, Tx, nullptr, Z,
        Cx, Tx, Dx, 4, nullptr, nullptr);
    // hT[s][c] = sum_t LT[s][t]*gh[c][t] + ht_b[c]; fused BN stat atomics
    // grid: 8 x (16 x 4) = 512
    gemm_mf<3, true><<<dim3(512), blk, 0, stream>>>(
        LT, sW, Tx, gh, sGH, Tx, hT, sX, Cx, psum, pssq,
        Tx, Cx, Tx, 16, nullptr, ht_b);
    bn_apply_T<<<dim3(Tx / 64, Cx / 64, Bx), blk, 0, stream>>>(
        inpt, hT, psum, pssq, gamma, beta, (float*)d_out);
}

// Round 9
// 224.088 us; speedup vs baseline: 4.7131x; 1.0072x over previous
//
#include <hip/hip_runtime.h>
#include <hip/hip_bf16.h>
#include <math.h>

#define Bx 8
#define Cx 512
#define Dx 256
#define Tx 2048
#define EPSx 1e-5f

typedef _Float16 h16;
typedef __attribute__((ext_vector_type(8))) _Float16 h16x8;
typedef __attribute__((ext_vector_type(8))) short s16x8;
typedef __attribute__((ext_vector_type(4))) float f32x4;

typedef __attribute__((address_space(3))) unsigned int lds_u32;
typedef __attribute__((address_space(1))) const unsigned int glb_u32;

// async 16B global -> LDS DMA. ldsp must be wave-uniform; HW adds lane*16.
__device__ __forceinline__ void cp16(void* ldsp, const void* g) {
    __builtin_amdgcn_global_load_lds((glb_u32*)g, (lds_u32*)ldsp, 16, 0, 0);
}

// ---------------------------------------------------------------------------
// MFMA GEMM core: acc[m][n] = sum_k A[m][k]*B[n][k], 2-byte dtypes (f16/bf16),
// tile 128 x TN (TN=128 or 64), BK=64 (0-conflict LDS layout), 4 waves (2x2),
// global_load_lds staging with XOR swizzle.
// Grid: 1-D, batch->XCD swizzle: b = id & 7 (r7: FETCH 147->41MB);
// rr = id >> 3; m0 = (rr % mBlk)*128; n0 = (rr / mBlk)*TN.
// Epilogue by MODE:
//   0: f16 out, + optional biasM[row] + biasN[col]                (projection)
//   1: bf16 out = acc * (1/Z[b*N+col])                            (gh' = gh/Z)
//   2: bf16 out = exp(acc); atomicAdd Z[b*N+col] += col sums      (logits)
//   3: f16 out = acc + biasN[col]; atomicAdd Cp[col]+=sum(v),
//      Z[col]+=sum(v^2) (fused BatchNorm stats)                   (big GEMM)
// ---------------------------------------------------------------------------
template<int MODE, bool BF, int TN>
__global__ __launch_bounds__(256, 4)
void gemm_mf(const h16* __restrict__ A, long aBatch, int lda,
             const h16* __restrict__ B, long bBatch, int ldb,
             void* __restrict__ C, long cBatch, int ldc,
             float* __restrict__ Cp, float* __restrict__ Z,
             int M, int N, int K, int mBlk,
             const float* __restrict__ biasM, const float* __restrict__ biasN) {
    constexpr int NJ = TN / 32;          // B-frags per wave (n-dir)
    __shared__ h16 As[128 * 64];
    __shared__ h16 Bs[TN * 64];
    const int tid  = threadIdx.x;
    const int lane = tid & 63, wid = tid >> 6;
    const int wm = (wid & 1) * 64, wn = (wid >> 1) * (TN / 2);
    const int lm = lane & 15, quad = lane >> 4;
    const unsigned id = blockIdx.x;
    const int b = id & 7;
    const unsigned rr = id >> 3;
    const int m0 = (rr % (unsigned)mBlk) * 128;
    const int n0 = (rr / (unsigned)mBlk) * TN;
    const h16* Ab = A + (size_t)b * aBatch + (size_t)m0 * lda;
    const h16* Bb = B + (size_t)b * bBatch + (size_t)n0 * ldb;

    const int srow  = tid >> 3;                 // row within 32-row group
    const int sclog = (tid & 7) ^ (srow & 7);   // logical k-chunk (XOR swizzle)
    char* ldsA = (char*)As + (tid & ~63) * 16;  // wave-uniform base
    char* ldsB = (char*)Bs + (tid & ~63) * 16;

    f32x4 acc[4][NJ] = {};

    for (int k0 = 0; k0 < K; k0 += 64) {
        __syncthreads();   // all waves done reading previous tile
#pragma unroll
        for (int i = 0; i < 4; i++) {
            int r = srow + 32 * i;
            cp16(ldsA + i * 4096, Ab + (size_t)r * lda + k0 + sclog * 8);
        }
#pragma unroll
        for (int i = 0; i < TN / 32; i++) {
            int r = srow + 32 * i;
            cp16(ldsB + i * 4096, Bb + (size_t)r * ldb + k0 + sclog * 8);
        }
        __syncthreads();   // drains vmcnt(0): tile resident
#pragma unroll
        for (int ks = 0; ks < 2; ks++) {
            s16x8 af[4], bf4[NJ];
#pragma unroll
            for (int i = 0; i < 4; i++) {
                int row = wm + 16 * i + lm;
                int st = (ks * 4 + quad) ^ (lm & 7);
                af[i] = *(const s16x8*)(As + row * 64 + st * 8);
            }
#pragma unroll
            for (int j = 0; j < NJ; j++) {
                int row = wn + 16 * j + lm;
                int st = (ks * 4 + quad) ^ (lm & 7);
                bf4[j] = *(const s16x8*)(Bs + row * 64 + st * 8);
            }
#pragma unroll
            for (int i = 0; i < 4; i++)
#pragma unroll
                for (int j = 0; j < NJ; j++) {
                    if constexpr (BF)
                        acc[i][j] = __builtin_amdgcn_mfma_f32_16x16x32_bf16(
                            af[i], bf4[j], acc[i][j], 0, 0, 0);
                    else
                        acc[i][j] = __builtin_amdgcn_mfma_f32_16x16x32_f16(
                            __builtin_bit_cast(h16x8, af[i]),
                            __builtin_bit_cast(h16x8, bf4[j]), acc[i][j], 0, 0, 0);
                }
        }
    }

    // epilogue: C/D layout col=lane&15, row=quad*4+reg
    if constexpr (MODE == 0) {
        h16* Cb = (h16*)C + (size_t)b * cBatch;
#pragma unroll
        for (int i = 0; i < 4; i++)
#pragma unroll
            for (int j = 0; j < NJ; j++) {
                int row = m0 + wm + 16 * i + quad * 4;
                int col = n0 + wn + 16 * j + lm;
                float bN = biasN ? biasN[col] : 0.0f;
#pragma unroll
                for (int r = 0; r < 4; r++) {
                    float v = acc[i][j][r] + bN;
                    if (biasM) v += biasM[row + r];
                    Cb[(size_t)(row + r) * ldc + col] = (h16)v;
                }
            }
    } else if constexpr (MODE == 1) {
        __hip_bfloat16* Cb = (__hip_bfloat16*)C + (size_t)b * cBatch;
#pragma unroll
        for (int j = 0; j < NJ; j++) {
            int col = n0 + wn + 16 * j + lm;
            float iz = 1.0f / Z[(size_t)b * N + col];
#pragma unroll
            for (int i = 0; i < 4; i++) {
                int row = m0 + wm + 16 * i + quad * 4;
#pragma unroll
                for (int r = 0; r < 4; r++)
                    Cb[(size_t)(row + r) * ldc + col] =
                        __float2bfloat16(acc[i][j][r] * iz);
            }
        }
    } else if constexpr (MODE == 2) {
        __syncthreads();                       // fragments consumed
        float* Zl = (float*)As;
        if (tid < TN) Zl[tid] = 0.0f;
        __syncthreads();
        __hip_bfloat16* Cb = (__hip_bfloat16*)C + (size_t)b * cBatch;
#pragma unroll
        for (int j = 0; j < NJ; j++) {
            int cl = wn + 16 * j + lm;
            int col = n0 + cl;
            float zp = 0.0f;
#pragma unroll
            for (int i = 0; i < 4; i++) {
                int row = m0 + wm + 16 * i + quad * 4;
#pragma unroll
                for (int r = 0; r < 4; r++) {
                    float e = __expf(acc[i][j][r]);
                    zp += e;
                    Cb[(size_t)(row + r) * ldc + col] = __float2bfloat16(e);
                }
            }
            atomicAdd(&Zl[cl], zp);
        }
        __syncthreads();
        if (tid < TN) atomicAdd(&Z[(size_t)b * N + n0 + tid], Zl[tid]);
    } else {  // MODE 3: f16 out + biasN, fused BN sum/sumsq atomics
        __syncthreads();                       // fragments consumed
        float* Sl = (float*)As;                // [0:TN) col sums
        float* Sq = Sl + TN;                   // [TN:2TN) col sumsq
        if (tid < 2 * TN) Sl[tid] = 0.0f;
        __syncthreads();
        h16* Cb = (h16*)C + (size_t)b * cBatch;
#pragma unroll
        for (int j = 0; j < NJ; j++) {
            int cl = wn + 16 * j + lm;
            int col = n0 + cl;
            float bN = biasN[col];
            float s = 0.0f, q = 0.0f;
#pragma unroll
            for (int i = 0; i < 4; i++) {
                int row = m0 + wm + 16 * i + quad * 4;
#pragma unroll
                for (int r = 0; r < 4; r++) {
                    float v = acc[i][j][r] + bN;
                    s += v;
                    q = fmaf(v, v, q);
                    Cb[(size_t)(row + r) * ldc + col] = (h16)v;
                }
            }
            atomicAdd(&Sl[cl], s);
            atomicAdd(&Sq[cl], q);
        }
        __syncthreads();
        if (tid < TN) {
            atomicAdd(&Cp[n0 + tid], Sl[tid]);
            atomicAdd(&Z[n0 + tid], Sq[tid]);
        }
    }
}

// ---------------------------------------------------------------------------
// Fused prep: z<8  -> inpt[b][c][t] fp32 -> xT[b][t][c] f16 (64x64 transpose)
//             z==8 -> weights->f16 concat, bias3, Z/psum/pssq zero-init.
// ---------------------------------------------------------------------------
__global__ __launch_bounds__(256)
void conv_prep(const float* __restrict__ inpt, h16* __restrict__ xT,
               const float* __restrict__ w0, const float* __restrict__ w1,
               const float* __restrict__ w2, const float* __restrict__ w3,
               const float* __restrict__ tb, const float* __restrict__ pb,
               const float* __restrict__ gb,
               h16* __restrict__ dst, float* __restrict__ bias3,
               float* __restrict__ Z, float* __restrict__ psum,
               float* __restrict__ pssq) {
    const int tid = threadIdx.x;
    if (blockIdx.z == 8) {
        int bx = blockIdx.y * 32 + blockIdx.x;          // 0..255
        // weights: 131072 float4 total, 512 per block
#pragma unroll
        for (int rep = 0; rep < 2; rep++) {
            int idx4 = bx * 512 + rep * 256 + tid;
            int arr = idx4 >> 15, local4 = idx4 & 32767;
            const float* srcs[4] = {w0, w1, w2, w3};
            float4 v = ((const float4*)srcs[arr])[local4];
            h16 o[4] = {(h16)v.x, (h16)v.y, (h16)v.z, (h16)v.w};
            *(uint2*)(dst + (size_t)arr * 131072 + (size_t)local4 * 4) = *(uint2*)o;
        }
        if (bx < 64) Z[bx * 256 + tid] = 0.0f;          // 16384 floats
        if (bx == 64) bias3[tid] = tb[tid];
        if (bx == 65) bias3[256 + tid] = pb[tid];
        if (bx == 66) bias3[512 + tid] = gb[tid];
        if (bx == 67) {
            psum[tid] = 0.0f; psum[tid + 256] = 0.0f;
            pssq[tid] = 0.0f; pssq[tid + 256] = 0.0f;
        }
        return;
    }
    __shared__ float lds[64][68];
    const int b = blockIdx.z;
    const int t0 = blockIdx.x * 64, c0 = blockIdx.y * 64;
    const int q = tid >> 4, k = tid & 15;
    const float* ib = inpt + (size_t)b * Cx * Tx;
#pragma unroll
    for (int i = 0; i < 4; i++) {
        int c = q + 16 * i;
        float4 v = *(const float4*)(ib + (size_t)(c0 + c) * Tx + t0 + 4 * k);
        *(float4*)&lds[c][4 * k] = v;
    }
    __syncthreads();
    h16* xb = xT + (size_t)b * Tx * Cx;
#pragma unroll
    for (int i = 0; i < 4; i++) {
        int t = q + 16 * i;
        h16 o[4];
#pragma unroll
        for (int j = 0; j < 4; j++) o[j] = (h16)lds[4 * k + j][t];
        *(uint2*)(xb + (size_t)(t0 + t) * Cx + c0 + 4 * k) = *(uint2*)o;
    }
}

// ---------------------------------------------------------------------------
// out[b][c][t] = inpt + gamma[c]*(hT[b][t][c]-mu)*rsig + beta[c]
// BN finalize fused: mu/rsig computed inline from psum/pssq.
// ---------------------------------------------------------------------------
__global__ __launch_bounds__(256)
void bn_apply_T(const float* __restrict__ inpt, const h16* __restrict__ hT,
                const float* __restrict__ psum, const float* __restrict__ pssq,
                const float* __restrict__ gamma, const float* __restrict__ beta,
                float* __restrict__ out) {
    __shared__ float lds[64][68];
    const int b = blockIdx.z, t0 = blockIdx.x * 64, c0 = blockIdx.y * 64;
    const int tid = threadIdx.x, q = tid >> 4, k = tid & 15;
    const h16* hb = hT + (size_t)b * Tx * Cx;
#pragma unroll
    for (int i = 0; i < 4; i++) {
        int t = q + 16 * i;
        uint2 raw = *(const uint2*)(hb + (size_t)(t0 + t) * Cx + c0 + 4 * k);
        const h16* hp = (const h16*)&raw;
        float4 v = make_float4((float)hp[0], (float)hp[1], (float)hp[2], (float)hp[3]);
        *(float4*)&lds[t][4 * k] = v;
    }
    __syncthreads();
    const float* ib = inpt + (size_t)b * Cx * Tx;
    float* ob = out + (size_t)b * Cx * Tx;
    const float invN = 1.0f / (float)(Bx * Tx);
#pragma unroll
    for (int i = 0; i < 4; i++) {
        int c = q + 16 * i;
        int cg = c0 + c;
        float mu = psum[cg] * invN;
        float var = pssq[cg] * invN - mu * mu;
        float rv = rsqrtf(var + EPSx);
        float ga = gamma[cg], be = beta[cg];
        float4 x = *(const float4*)(ib + (size_t)cg * Tx + t0 + 4 * k);
        float4 o;
        o.x = x.x + ga * (lds[4 * k + 0][c] - mu) * rv + be;
        o.y = x.y + ga * (lds[4 * k + 1][c] - mu) * rv + be;
        o.z = x.z + ga * (lds[4 * k + 2][c] - mu) * rv + be;
        o.w = x.w + ga * (lds[4 * k + 3][c] - mu) * rv + be;
        *(float4*)(ob + (size_t)cg * Tx + t0 + 4 * k) = o;
    }
}

// ---------------------------------------------------------------------------
// Workspace (bytes, total ~121 MiB):
//   xT    @0            16,777,216  (f16 [b][t][c] -> hT reuse)
//   w4    @16,777,216    1,048,576  (theta|phi|g|ht f16; wTPG=768x512, wHt)
//   bias3 @17,825,792        3,072  (theta_b||phi_b||g_b)
//   Z     @17,828,864       65,536  (fp32 exp-row-sums [b][t])
//   psum  @17,894,400        2,048  (fp32 BN channel sums)
//   pssq  @17,896,448        2,048
//   thpg  @17,902,592   25,165,824  (f16 [b][t][theta||phi||g], ld 768)
//   gh    @43,068,416   16,777,216  (bf16 gh' = (ht_w·g)/Z, [b][c][t])
//   LT    @59,845,632   67,108,864  (bf16 exp-logits [b][s][t])
// ---------------------------------------------------------------------------
extern "C" void kernel_launch(void* const* d_in, const int* in_sizes, int n_in,
                              void* d_out, int out_size, void* d_ws, size_t ws_size,
                              hipStream_t stream) {
    const float* inpt    = (const float*)d_in[0];
    const float* theta_w = (const float*)d_in[1];
    const float* theta_b = (const float*)d_in[2];
    const float* phi_w   = (const float*)d_in[3];
    const float* phi_b   = (const float*)d_in[4];
    const float* g_w     = (const float*)d_in[5];
    const float* g_b     = (const float*)d_in[6];
    const float* ht_w    = (const float*)d_in[7];
    const float* ht_b    = (const float*)d_in[8];
    const float* gamma   = (const float*)d_in[9];
    const float* beta    = (const float*)d_in[10];

    char* ws = (char*)d_ws;
    h16*   xT    = (h16*)(ws + 0);
    h16*   w4    = (h16*)(ws + 16777216);     // wTPG = w4 (768 rows x 512)
    h16*   wHt   = w4 + 393216;               // 512 rows x 256
    float* bias3 = (float*)(ws + 17825792);
    float* Z     = (float*)(ws + 17828864);
    float* psum  = (float*)(ws + 17894400);
    float* pssq  = (float*)(ws + 17896448);
    h16*   thpg  = (h16*)(ws + 17902592);
    h16*   gh    = (h16*)(ws + 43068416);     // bf16 bits
    h16*   LT    = (h16*)(ws + 59845632);     // bf16 bits
    h16*   hT    = xT;                        // reuse: xT dead after proj GEMM

    const long sX  = (long)Tx * Cx;    // 1,048,576 (xT, hT)
    const long sTP = (long)Tx * 768;   // 1,572,864 (thpg)
    const long sGH = (long)Cx * Tx;    // 1,048,576 (gh)
    const long sW  = (long)Tx * Tx;    // 4,194,304 (LT)

    dim3 blk(256);
    // fused input transpose + weight conversion + zero-init
    conv_prep<<<dim3(Tx / 64, Cx / 64, Bx + 1), blk, 0, stream>>>(
        inpt, xT, theta_w, phi_w, g_w, ht_w, theta_b, phi_b, g_b,
        w4, bias3, Z, psum, pssq);
    // thpg[t][n] = sum_c xT[t][c]*(theta||phi||g)[n][c] + bias3[n]   (f16)
    // grid: 8 batches x (16 m-blk x 6 n-blk) = 768
    gemm_mf<0, false, 128><<<dim3(768), blk, 0, stream>>>(
        xT, sX, Cx, w4, 0, Cx, thpg, sTP, 768, nullptr, nullptr,
        Tx, 768, Cx, 16, nullptr, bias3);
    // LT[s][t] = exp(sum_d phi[s][d]*theta[t][d]) bf16; Z[t] += col sums
    // grid: 8 x (16 x 16) = 2048
    gemm_mf<2, false, 128><<<dim3(2048), blk, 0, stream>>>(
        thpg + 256, sTP, 768, thpg, sTP, 768, LT, sW, Tx, nullptr, Z,
        Tx, Tx, Dx, 16, nullptr, nullptr);
    // gh[c][t] = (sum_d ht_w[c][d]*g[t][d]) / Z[t]   (bf16)
    // grid: 8 x (4 x 16) = 512
    gemm_mf<1, false, 128><<<dim3(512), blk, 0, stream>>>(
        wHt, 0, Dx, thpg + 512, sTP, 768, gh, sGH, Tx, nullptr, Z,
        Cx, Tx, Dx, 4, nullptr, nullptr);
    // hT[s][c] = sum_t LT[s][t]*gh[c][t] + ht_b[c]; fused BN stat atomics
    // TN=64 tile: grid 8 x (16 m x 8 n) = 1024 blocks = 4/CU
    gemm_mf<3, true, 64><<<dim3(1024), blk, 0, stream>>>(
        LT, sW, Tx, gh, sGH, Tx, hT, sX, Cx, psum, pssq,
        Tx, Cx, Tx, 16, nullptr, ht_b);
    bn_apply_T<<<dim3(Tx / 64, Cx / 64, Bx), blk, 0, stream>>>(
        inpt, hT, psum, pssq, gamma, beta, (float*)d_out);
}